// Round 4
// baseline (192.006 us; speedup 1.0000x reference)
//
#include <hip/hip_runtime.h>
#include <hip/hip_bf16.h>
#include <math.h>

#define N_NODES 50000
#define N_EDGES 1600000
#define D_IN 128
#define D_OUT 32
#define ALPHA 0.2f

#define NB   1021    // one bucket per RPB rows (1021*49 = 50029 >= 50000)
#define NBP  1024    // padded bucket count for gcount array
#define RPB  49      // rows per bucket
#define CAP  2048    // record slots per bucket (mean ~1567, +12 sigma)
#define GST  16      // gcount stride in ints: one counter per 64B line
#define EPT  4       // edges per thread in edge kernel (one int4 per stream)
#define EBK  256     // edge kernel block size
#define EB   (EPT * EBK)                    // 1024 edges per edge-block
#define NEB  ((N_EDGES + EB - 1) / EB)      // 1563 edge blocks
#define XNPB 32      // nodes per GEMM block
#define NXB  ((N_NODES + XNPB - 1) / XNPB)  // 1563 GEMM blocks
#define XLS  33      // padded X-tile stride in float4 (bank-conflict fix)

// Monotone float<->int key (involution). Works with signed min/max.
__device__ __forceinline__ int enc_f(float x) {
    int i = __float_as_int(x);
    return i >= 0 ? i : (i ^ 0x7fffffff);
}
__device__ __forceinline__ float dec_f(int k) {
    return __int_as_float(k >= 0 ? k : (k ^ 0x7fffffff));
}
__device__ __forceinline__ unsigned short f2bf(float x) {
    __hip_bfloat16 h = __float2bfloat16(x);
    return *(unsigned short*)&h;
}
__device__ __forceinline__ float bf2f(unsigned short u) {
    return __uint_as_float((unsigned)u << 16);
}

// K1: GEMM X@W -> Xpb (bf16) with s0/s1 epilogue (s0=(X@W).a0 from the f32
// row already in registers). Single X pass. Padded-stride LDS X tile
// (conflict-free). Block 0 zeroes the padded gcount array (harness poisons
// the workspace every iteration, so this init is required).
__global__ __launch_bounds__(256) void k_gemm(const float* __restrict__ X,
                                              const float* __restrict__ W,
                                              const float* __restrict__ a0,
                                              const float* __restrict__ a1,
                                              unsigned short* __restrict__ Xpb,
                                              float* __restrict__ s0,
                                              float* __restrict__ s1,
                                              int* __restrict__ gcount) {
    __shared__ float4 Wl4[1024];        // 16 KB
    __shared__ float4 Xl4[XNPB * XLS];  // 16.9 KB (padded)
    const int tid = threadIdx.x;
    if (blockIdx.x == 0) {
        int4* g4 = (int4*)gcount;
#pragma unroll
        for (int i = 0; i < NBP * GST / 4 / 256; ++i)
            g4[tid + 256 * i] = make_int4(0, 0, 0, 0);
    }
    const int node0 = blockIdx.x * XNPB;
    {
        const float4* W4 = (const float4*)W;
#pragma unroll
        for (int i = 0; i < 4; ++i) Wl4[tid + 256 * i] = W4[tid + 256 * i];
        const float4* X4 = (const float4*)X + (size_t)node0 * (D_IN / 4);
        const int lim = (min(XNPB, N_NODES - node0)) * (D_IN / 4);
#pragma unroll
        for (int i = 0; i < 4; ++i) {
            const int idx = tid + 256 * i;
            const float4 v = (idx < lim) ? X4[idx]
                                         : make_float4(0.f, 0.f, 0.f, 0.f);
            Xl4[(idx >> 5) * XLS + (idx & 31)] = v;
        }
    }
    __syncthreads();
    const int g = tid >> 3;  // node within block (0..31)
    const int l = tid & 7;   // lane -> dims [4l, 4l+4)
    const int node = node0 + g;
    const float4* xr = &Xl4[g * XLS];
    float ax = 0.f, ay = 0.f, az = 0.f, aw = 0.f;
#pragma unroll 4
    for (int kk = 0; kk < D_IN / 4; ++kk) {
        const float4 xv = xr[kk];
        const float4 w0 = Wl4[(4 * kk + 0) * 8 + l];
        const float4 w1 = Wl4[(4 * kk + 1) * 8 + l];
        const float4 w2 = Wl4[(4 * kk + 2) * 8 + l];
        const float4 w3 = Wl4[(4 * kk + 3) * 8 + l];
        ax += xv.x * w0.x + xv.y * w1.x + xv.z * w2.x + xv.w * w3.x;
        ay += xv.x * w0.y + xv.y * w1.y + xv.z * w2.y + xv.w * w3.y;
        az += xv.x * w0.z + xv.y * w1.z + xv.z * w2.z + xv.w * w3.z;
        aw += xv.x * w0.w + xv.y * w1.w + xv.z * w2.w + xv.w * w3.w;
    }
    if (node < N_NODES) {
        uint2 pk;
        pk.x = ((unsigned)f2bf(ay) << 16) | f2bf(ax);
        pk.y = ((unsigned)f2bf(aw) << 16) | f2bf(az);
        ((uint2*)Xpb)[(size_t)node * 8 + l] = pk;
        // score epilogue: dot f32 Xp row with a0/a1, reduce over 8 lanes
        const float4 av0 = ((const float4*)a0)[l];
        const float4 av1 = ((const float4*)a1)[l];
        float v0 = ax * av0.x + ay * av0.y + az * av0.z + aw * av0.w;
        float v1 = ax * av1.x + ay * av1.y + az * av1.z + aw * av1.w;
#pragma unroll
        for (int m = 4; m >= 1; m >>= 1) {
            v0 += __shfl_xor(v0, m);
            v1 += __shfl_xor(v1, m);
        }
        if (l == 0) { s0[node] = v0; s1[node] = v1; }
    }
}

// K2: edge pass v3 — ZERO LDS in the hot path, zero barriers before the
// epilogue. Per edge: score = leaky(s0[r]+s1[c]); slot = one direct
// atomicAdd-with-return on the padded per-bucket counter; 8B record store
// {lr:6|col:16, score}. R1/R3 showed the two-level LDS-hist+merge scheme
// is NOT cheaper — it just adds 5 barrier phases and caps occupancy at 22%.
// Here: no LDS -> ~24 waves/CU; min/max goes to a PRIVATE mm[bid] slot
// (no shared-line atomics anywhere; k_bucket reduces the table).
__global__ __launch_bounds__(256) void k_edge(const int* __restrict__ row,
                                              const int* __restrict__ col,
                                              const float* __restrict__ s0,
                                              const float* __restrict__ s1,
                                              int* __restrict__ gcount,
                                              int2* __restrict__ mm,
                                              uint2* __restrict__ gEdges) {
    __shared__ int smn[4], smx[4];
    const int tid = threadIdx.x;
    const int base = blockIdx.x * EB;
    int kmin = 0x7fffffff, kmax = 0x80000000;
    if (base + EB <= N_EDGES) {   // full block: one int4 per stream
        const int4 r4 = ((const int4*)(row + base))[tid];
        const int4 c4 = ((const int4*)(col + base))[tid];
        const int rr[4] = {r4.x, r4.y, r4.z, r4.w};
        const int cc[4] = {c4.x, c4.y, c4.z, c4.w};
        float sr[4], sc[4];
#pragma unroll
        for (int j = 0; j < 4; ++j) { sr[j] = s0[rr[j]]; sc[j] = s1[cc[j]]; }
#pragma unroll
        for (int j = 0; j < 4; ++j) {
            float a = sr[j] + sc[j];
            a = a > 0.f ? a : ALPHA * a;
            const int k = enc_f(a);
            kmin = min(kmin, k);
            kmax = max(kmax, k);
            const unsigned r = (unsigned)rr[j];
            const unsigned b = r / RPB;
            const unsigned lr = r - b * RPB;
            const int pos = atomicAdd(&gcount[b << 4], 1);
            if (pos < CAP)
                gEdges[(size_t)b * CAP + pos] =
                    make_uint2((lr << 16) | (unsigned)cc[j],
                               (unsigned)__float_as_int(a));
        }
    } else {                      // tail block: scalar guarded
#pragma unroll
        for (int j = 0; j < 4; ++j) {
            const int e = base + j * EBK + tid;
            if (e < N_EDGES) {
                const int rv = row[e];
                const int cv = col[e];
                float a = s0[rv] + s1[cv];
                a = a > 0.f ? a : ALPHA * a;
                const int k = enc_f(a);
                kmin = min(kmin, k);
                kmax = max(kmax, k);
                const unsigned r = (unsigned)rv;
                const unsigned b = r / RPB;
                const unsigned lr = r - b * RPB;
                const int pos = atomicAdd(&gcount[b << 4], 1);
                if (pos < CAP)
                    gEdges[(size_t)b * CAP + pos] =
                        make_uint2((lr << 16) | (unsigned)cv,
                                   (unsigned)__float_as_int(a));
            }
        }
    }
    // epilogue: block min/max -> private slot (no contended atomics)
#pragma unroll
    for (int m = 32; m >= 1; m >>= 1) {
        kmin = min(kmin, __shfl_xor(kmin, m));
        kmax = max(kmax, __shfl_xor(kmax, m));
    }
    const int wave = tid >> 6;
    if ((tid & 63) == 0) { smn[wave] = kmin; smx[wave] = kmax; }
    __syncthreads();
    if (tid == 0) {
#pragma unroll
        for (int w = 1; w < 4; ++w) {
            kmin = min(kmin, smn[w]);
            kmax = max(kmax, smx[w]);
        }
        mm[blockIdx.x] = make_int2(kmin, kmax);
    }
}

// K3: one 512-thread block per 49-row bucket (1021 blocks, ~12.4 KB LDS).
// prologue: reduce the 1563-entry per-block minmax table (~12.5 KB
//           L2-resident read, ~0.3us);
// pass 1:   LDS histogram of this bucket's rows (49 bins);
// pass 2:   counting-sort scatter {col:u16, exp(minmaxnorm(score))};
// rows:     32 row-processors x 16 lanes (2 bf16 dims per lane via one u32
//           load), 4-way unrolled register accumulators, float2 out.
__global__ __launch_bounds__(512, 8) void k_bucket(const int* __restrict__ gcount,
                                                   const uint2* __restrict__ gEdges,
                                                   const unsigned short* __restrict__ Xpb,
                                                   const int2* __restrict__ mm,
                                                   float* __restrict__ out) {
    __shared__ unsigned short scol[CAP]; // 4 KB
    __shared__ float swt[CAP];           // 8 KB
    __shared__ int off[RPB + 1];
    __shared__ int cur[RPB];
    __shared__ int rmn[8], rmx[8];
    __shared__ float s_mn, s_inv;
    const int b = blockIdx.x;
    const int t = threadIdx.x;
    const int cnt = min(gcount[b << 4], CAP);   // padded gcount
    const uint2* eb = gEdges + (size_t)b * CAP;

    // prologue: global min/max from the per-edge-block table
    int kmn = 0x7fffffff, kmx = 0x80000000;
    for (int i = t; i < NEB; i += 512) {
        const int2 v = mm[i];
        kmn = min(kmn, v.x);
        kmx = max(kmx, v.y);
    }
#pragma unroll
    for (int m = 32; m >= 1; m >>= 1) {
        kmn = min(kmn, __shfl_xor(kmn, m));
        kmx = max(kmx, __shfl_xor(kmx, m));
    }
    if ((t & 63) == 0) { rmn[t >> 6] = kmn; rmx[t >> 6] = kmx; }
    if (t < RPB) cur[t] = 0;  // temp hist (same barrier covers this)
    __syncthreads();
    if (t == 0) {
#pragma unroll
        for (int w = 1; w < 8; ++w) {
            kmn = min(kmn, rmn[w]);
            kmx = max(kmx, rmx[w]);
        }
        const float mn = dec_f(kmn);
        const float mx = dec_f(kmx);
        s_mn = mn;
        s_inv = 1.0f / (mx - mn);
    }
    // pass 1: histogram (t0 finished its reduce before reaching the barrier)
    for (int i = t; i < cnt; i += 512) atomicAdd(&cur[eb[i].x >> 16], 1);
    __syncthreads();
    if (t == 0) {
        int run = 0;
#pragma unroll
        for (int r = 0; r < RPB; ++r) { off[r] = run; run += cur[r]; }
        off[RPB] = run;
    }
    __syncthreads();
    if (t < RPB) cur[t] = off[t];
    __syncthreads();
    const float mn = s_mn;
    const float inv = s_inv;
    // pass 2: counting-sort scatter (exp computed once per edge)
    for (int i = t; i < cnt; i += 512) {
        const uint2 e = eb[i];
        const int lr = (int)(e.x >> 16);
        const int p = atomicAdd(&cur[lr], 1);
        if (p < CAP) {
            scol[p] = (unsigned short)(e.x & 0xFFFFu);
            swt[p] = __expf((__int_as_float(e.y) - mn) * inv);
        }
    }
    __syncthreads();

    // row processing: 32 processors x 16 lanes, 2 dims/lane, 4-way unroll
    const int proc = t >> 4;  // 0..31
    const int d2 = t & 15;    // dims [2*d2, 2*d2+1]
    const unsigned* Xp32 = (const unsigned*)Xpb;
    for (int lr = proc; lr < RPB; lr += 32) {
        const int s = off[lr];
        const int e2 = off[lr + 1];
        float pa0 = 0.f, pa1 = 0.f, pa2 = 0.f, pa3 = 0.f;
        float pb0 = 0.f, pb1 = 0.f, pb2 = 0.f, pb3 = 0.f;
        float w0s = 0.f, w1s = 0.f, w2s = 0.f, w3s = 0.f;
        int i = s;
        for (; i + 3 < e2; i += 4) {
            const int c0 = scol[i];
            const int c1 = scol[i + 1];
            const int c2 = scol[i + 2];
            const int c3 = scol[i + 3];
            const float w0 = swt[i];
            const float w1 = swt[i + 1];
            const float w2 = swt[i + 2];
            const float w3 = swt[i + 3];
            const unsigned u0 = Xp32[(size_t)c0 * 16 + d2];
            const unsigned u1 = Xp32[(size_t)c1 * 16 + d2];
            const unsigned u2 = Xp32[(size_t)c2 * 16 + d2];
            const unsigned u3 = Xp32[(size_t)c3 * 16 + d2];
            pa0 += w0 * bf2f((unsigned short)(u0 & 0xFFFFu));
            pb0 += w0 * bf2f((unsigned short)(u0 >> 16));
            pa1 += w1 * bf2f((unsigned short)(u1 & 0xFFFFu));
            pb1 += w1 * bf2f((unsigned short)(u1 >> 16));
            pa2 += w2 * bf2f((unsigned short)(u2 & 0xFFFFu));
            pb2 += w2 * bf2f((unsigned short)(u2 >> 16));
            pa3 += w3 * bf2f((unsigned short)(u3 & 0xFFFFu));
            pb3 += w3 * bf2f((unsigned short)(u3 >> 16));
            w0s += w0; w1s += w1; w2s += w2; w3s += w3;
        }
        for (; i < e2; ++i) {
            const float w = swt[i];
            const unsigned u = Xp32[(size_t)scol[i] * 16 + d2];
            pa0 += w * bf2f((unsigned short)(u & 0xFFFFu));
            pb0 += w * bf2f((unsigned short)(u >> 16));
            w0s += w;
        }
        const int r = b * RPB + lr;
        if (r < N_NODES) {
            const float ws = w0s + w1s + w2s + w3s;
            float2 o;
            o.x = (pa0 + pa1 + pa2 + pa3) / ws;
            o.y = (pb0 + pb1 + pb2 + pb3) / ws;
            ((float2*)out)[(size_t)r * 16 + d2] = o;
        }
    }
}

extern "C" void kernel_launch(void* const* d_in, const int* in_sizes, int n_in,
                              void* d_out, int out_size, void* d_ws, size_t ws_size,
                              hipStream_t stream) {
    const float* X  = (const float*)d_in[0];
    const float* W  = (const float*)d_in[1];
    const float* a0 = (const float*)d_in[2];
    const float* a1 = (const float*)d_in[3];
    const int* row  = (const int*)d_in[4];
    const int* col  = (const int*)d_in[5];
    float* out = (float*)d_out;

    // Workspace layout (4B units):
    // [pad: 64][gcount padded: NBP*GST = 16384][mm: 3200]
    // [s0: 50048][s1: 50048][Xpb: 800000 u32][gEdges: NB*CAP uint2] ~21 MB
    float* ws = (float*)d_ws;
    int*   gcount = (int*)ws + 64;
    int2*  mm = (int2*)((int*)ws + 64 + NBP * GST);
    float* s0 = ws + 64 + NBP * GST + 3200;
    float* s1 = s0 + 50048;
    unsigned short* Xpb = (unsigned short*)(s1 + 50048);
    uint2* gEdges = (uint2*)(s1 + 50048 + 800000);

    k_gemm<<<NXB, 256, 0, stream>>>(X, W, a0, a1, Xpb, s0, s1, gcount);
    k_edge<<<NEB, 256, 0, stream>>>(row, col, s0, s1, gcount, mm, gEdges);
    k_bucket<<<NB, 512, 0, stream>>>(gcount, gEdges, Xpb, mm, out);
}

// Round 5
// 178.249 us; speedup vs baseline: 1.0772x; 1.0772x over previous
//
#include <hip/hip_runtime.h>
#include <hip/hip_bf16.h>
#include <math.h>

#define N_NODES 50000
#define N_EDGES 1600000
#define D_IN 128
#define D_OUT 32
#define ALPHA 0.2f

#define NB   1021    // one bucket per RPB rows (1021*49 = 50029 >= 50000)
#define NBP  1024    // padded bucket count for gcount array
#define RPB  49      // rows per bucket
#define CAP  2048    // record slots per bucket (mean ~1567, +12 sigma)
#define GST  16      // gcount stride in ints: one counter per 64B line
#define EPT  4       // edges per thread in edge kernel (one int4 per stream)
#define EBK  256     // edge kernel block size
#define EB   (EPT * EBK)                    // 1024 edges per edge-block
#define NEB  ((N_EDGES + EB - 1) / EB)      // 1563 edge blocks
#define XNPB 32      // nodes per GEMM block
#define NXB  ((N_NODES + XNPB - 1) / XNPB)  // 1563 GEMM blocks
#define XLS  33      // padded X-tile stride in float4 (bank-conflict fix)

// Monotone float<->int key (involution). Works with signed min/max.
__device__ __forceinline__ int enc_f(float x) {
    int i = __float_as_int(x);
    return i >= 0 ? i : (i ^ 0x7fffffff);
}
__device__ __forceinline__ float dec_f(int k) {
    return __int_as_float(k >= 0 ? k : (k ^ 0x7fffffff));
}
__device__ __forceinline__ unsigned short f2bf(float x) {
    __hip_bfloat16 h = __float2bfloat16(x);
    return *(unsigned short*)&h;
}
__device__ __forceinline__ float bf2f(unsigned short u) {
    return __uint_as_float((unsigned)u << 16);
}

// K1: GEMM X@W -> Xpb (bf16) with s0/s1 epilogue (s0=(X@W).a0 from the f32
// row already in registers). Single X pass. Padded-stride LDS X tile
// (conflict-free). Block 0 zeroes the padded gcount array (harness poisons
// the workspace every iteration, so this init is required).
__global__ __launch_bounds__(256) void k_gemm(const float* __restrict__ X,
                                              const float* __restrict__ W,
                                              const float* __restrict__ a0,
                                              const float* __restrict__ a1,
                                              unsigned short* __restrict__ Xpb,
                                              float* __restrict__ s0,
                                              float* __restrict__ s1,
                                              int* __restrict__ gcount) {
    __shared__ float4 Wl4[1024];        // 16 KB
    __shared__ float4 Xl4[XNPB * XLS];  // 16.9 KB (padded)
    const int tid = threadIdx.x;
    if (blockIdx.x == 0) {
        int4* g4 = (int4*)gcount;
#pragma unroll
        for (int i = 0; i < NBP * GST / 4 / 256; ++i)
            g4[tid + 256 * i] = make_int4(0, 0, 0, 0);
    }
    const int node0 = blockIdx.x * XNPB;
    {
        const float4* W4 = (const float4*)W;
#pragma unroll
        for (int i = 0; i < 4; ++i) Wl4[tid + 256 * i] = W4[tid + 256 * i];
        const float4* X4 = (const float4*)X + (size_t)node0 * (D_IN / 4);
        const int lim = (min(XNPB, N_NODES - node0)) * (D_IN / 4);
#pragma unroll
        for (int i = 0; i < 4; ++i) {
            const int idx = tid + 256 * i;
            const float4 v = (idx < lim) ? X4[idx]
                                         : make_float4(0.f, 0.f, 0.f, 0.f);
            Xl4[(idx >> 5) * XLS + (idx & 31)] = v;
        }
    }
    __syncthreads();
    const int g = tid >> 3;  // node within block (0..31)
    const int l = tid & 7;   // lane -> dims [4l, 4l+4)
    const int node = node0 + g;
    const float4* xr = &Xl4[g * XLS];
    float ax = 0.f, ay = 0.f, az = 0.f, aw = 0.f;
#pragma unroll 4
    for (int kk = 0; kk < D_IN / 4; ++kk) {
        const float4 xv = xr[kk];
        const float4 w0 = Wl4[(4 * kk + 0) * 8 + l];
        const float4 w1 = Wl4[(4 * kk + 1) * 8 + l];
        const float4 w2 = Wl4[(4 * kk + 2) * 8 + l];
        const float4 w3 = Wl4[(4 * kk + 3) * 8 + l];
        ax += xv.x * w0.x + xv.y * w1.x + xv.z * w2.x + xv.w * w3.x;
        ay += xv.x * w0.y + xv.y * w1.y + xv.z * w2.y + xv.w * w3.y;
        az += xv.x * w0.z + xv.y * w1.z + xv.z * w2.z + xv.w * w3.z;
        aw += xv.x * w0.w + xv.y * w1.w + xv.z * w2.w + xv.w * w3.w;
    }
    if (node < N_NODES) {
        uint2 pk;
        pk.x = ((unsigned)f2bf(ay) << 16) | f2bf(ax);
        pk.y = ((unsigned)f2bf(aw) << 16) | f2bf(az);
        ((uint2*)Xpb)[(size_t)node * 8 + l] = pk;
        // score epilogue: dot f32 Xp row with a0/a1, reduce over 8 lanes
        const float4 av0 = ((const float4*)a0)[l];
        const float4 av1 = ((const float4*)a1)[l];
        float v0 = ax * av0.x + ay * av0.y + az * av0.z + aw * av0.w;
        float v1 = ax * av1.x + ay * av1.y + az * av1.z + aw * av1.w;
#pragma unroll
        for (int m = 4; m >= 1; m >>= 1) {
            v0 += __shfl_xor(v0, m);
            v1 += __shfl_xor(v1, m);
        }
        if (l == 0) { s0[node] = v0; s1[node] = v1; }
    }
}

// K2: edge pass v4 — two-level LDS slot allocation (R1 structure: preserves
// store coalescing + batches global claims ~640/block), but re-engineered
// for occupancy, which was R1's real limit (782 blocks -> 12 waves/CU,
// 18.5% occ). Changes vs R1:
//  * EB=1024 -> 1563 blocks (~6 blocks/CU, 24 waves/CU);
//  * hist and lcur PACKED as u16 pairs in u32 words (counts<=~1800, bases
//    <2048 so both halves fit): LDS 8.7KB -> 4.2KB, half the LDS-atomic
//    words; atomicAdd of 1 / 1<<16 returns both halves for the scatter;
//  * padded gcount claims (1 counter / 64B line);
//  * min/max -> private mm[bid] slot (zero contended atomics; k_bucket
//    prologue reduces the 1563-entry table).
// R4 (no-LDS per-edge direct claim) was 84us: per-edge same-line RMW chain
// + 8x store amplification (WRITE 91MB). Don't go back.
__global__ __launch_bounds__(256) void k_edge(const int* __restrict__ row,
                                              const int* __restrict__ col,
                                              const float* __restrict__ s0,
                                              const float* __restrict__ s1,
                                              int* __restrict__ gcount,
                                              int2* __restrict__ mm,
                                              uint2* __restrict__ gEdges) {
    __shared__ unsigned histP[NBP / 2];  // 2 KB: packed u16 counts
    __shared__ unsigned lcurP[NBP / 2];  // 2 KB: packed u16 cursors
    __shared__ int smn[4], smx[4];
    const int tid = threadIdx.x;
#pragma unroll
    for (int i = 0; i < NBP / 2 / EBK; ++i) histP[tid + EBK * i] = 0u;
    __syncthreads();
    const int base = blockIdx.x * EB;
    unsigned pb[EPT];  // bucket
    unsigned pr[EPT];  // (lr:6|col:16)
    float    fa[EPT];  // leaky-relu'd score
    int cnt = 0;
    int kmin = 0x7fffffff, kmax = 0x80000000;
    if (base + EB <= N_EDGES) {   // full block: one int4 per stream
        const int4 r4 = ((const int4*)(row + base))[tid];
        const int4 c4 = ((const int4*)(col + base))[tid];
        const int rr[4] = {r4.x, r4.y, r4.z, r4.w};
        const int cc[4] = {c4.x, c4.y, c4.z, c4.w};
        float sr[4], sc[4];
#pragma unroll
        for (int j = 0; j < 4; ++j) { sr[j] = s0[rr[j]]; sc[j] = s1[cc[j]]; }
#pragma unroll
        for (int j = 0; j < 4; ++j) {
            float a = sr[j] + sc[j];
            a = a > 0.f ? a : ALPHA * a;
            const int k = enc_f(a);
            kmin = min(kmin, k);
            kmax = max(kmax, k);
            const unsigned r = (unsigned)rr[j];
            const unsigned b = r / RPB;
            const unsigned lr = r - b * RPB;
            pb[cnt] = b;
            pr[cnt] = (lr << 16) | (unsigned)cc[j];
            fa[cnt] = a;
            ++cnt;
            atomicAdd(&histP[b >> 1], (b & 1) ? (1u << 16) : 1u);
        }
    } else {                      // tail block: scalar guarded
#pragma unroll
        for (int j = 0; j < 4; ++j) {
            const int e = base + j * EBK + tid;
            if (e < N_EDGES) {
                const int rv = row[e];
                const int cv = col[e];
                float a = s0[rv] + s1[cv];
                a = a > 0.f ? a : ALPHA * a;
                const int k = enc_f(a);
                kmin = min(kmin, k);
                kmax = max(kmax, k);
                const unsigned r = (unsigned)rv;
                const unsigned b = r / RPB;
                const unsigned lr = r - b * RPB;
                pb[cnt] = b;
                pr[cnt] = (lr << 16) | (unsigned)cv;
                fa[cnt] = a;
                ++cnt;
                atomicAdd(&histP[b >> 1], (b & 1) ? (1u << 16) : 1u);
            }
        }
    }
    __syncthreads();
    // merge: claim a contiguous global range per touched bucket; pack bases
    for (int p = tid; p < NBP / 2; p += EBK) {
        const unsigned w = histP[p];
        const unsigned h0 = w & 0xFFFFu;
        const unsigned h1 = w >> 16;
        unsigned b0 = 0, b1 = 0;
        if (h0) b0 = (unsigned)atomicAdd(&gcount[(2 * p) << 4], (int)h0);
        if (h1) b1 = (unsigned)atomicAdd(&gcount[(2 * p + 1) << 4], (int)h1);
        lcurP[p] = b0 | (b1 << 16);
    }
    __syncthreads();
    // scatter: LDS packed cursor gives each record a mostly-sequential slot
    for (int j = 0; j < cnt; ++j) {
        const unsigned b = pb[j];
        const unsigned old =
            atomicAdd(&lcurP[b >> 1], (b & 1) ? (1u << 16) : 1u);
        const unsigned pos = (b & 1) ? (old >> 16) : (old & 0xFFFFu);
        if (pos < CAP)
            gEdges[(size_t)b * CAP + pos] =
                make_uint2(pr[j], (unsigned)__float_as_int(fa[j]));
    }
    // epilogue: block min/max -> private slot (no contended atomics)
#pragma unroll
    for (int m = 32; m >= 1; m >>= 1) {
        kmin = min(kmin, __shfl_xor(kmin, m));
        kmax = max(kmax, __shfl_xor(kmax, m));
    }
    const int wave = tid >> 6;
    if ((tid & 63) == 0) { smn[wave] = kmin; smx[wave] = kmax; }
    __syncthreads();
    if (tid == 0) {
#pragma unroll
        for (int w = 1; w < 4; ++w) {
            kmin = min(kmin, smn[w]);
            kmax = max(kmax, smx[w]);
        }
        mm[blockIdx.x] = make_int2(kmin, kmax);
    }
}

// K3: one 512-thread block per 49-row bucket (1021 blocks, ~12.4 KB LDS).
// prologue: reduce the 1563-entry per-block minmax table (L2-hot, ~0.3us);
// pass 1:   LDS histogram of this bucket's rows (49 bins);
// pass 2:   counting-sort scatter {col:u16, exp(minmaxnorm(score))};
// rows:     32 row-processors x 16 lanes (2 bf16 dims per lane via one u32
//           load), 4-way unrolled register accumulators, float2 out.
__global__ __launch_bounds__(512, 8) void k_bucket(const int* __restrict__ gcount,
                                                   const uint2* __restrict__ gEdges,
                                                   const unsigned short* __restrict__ Xpb,
                                                   const int2* __restrict__ mm,
                                                   float* __restrict__ out) {
    __shared__ unsigned short scol[CAP]; // 4 KB
    __shared__ float swt[CAP];           // 8 KB
    __shared__ int off[RPB + 1];
    __shared__ int cur[RPB];
    __shared__ int rmn[8], rmx[8];
    __shared__ float s_mn, s_inv;
    const int b = blockIdx.x;
    const int t = threadIdx.x;
    const int cnt = min(gcount[b << 4], CAP);   // padded gcount
    const uint2* eb = gEdges + (size_t)b * CAP;

    // prologue: global min/max from the per-edge-block table
    int kmn = 0x7fffffff, kmx = 0x80000000;
    for (int i = t; i < NEB; i += 512) {
        const int2 v = mm[i];
        kmn = min(kmn, v.x);
        kmx = max(kmx, v.y);
    }
#pragma unroll
    for (int m = 32; m >= 1; m >>= 1) {
        kmn = min(kmn, __shfl_xor(kmn, m));
        kmx = max(kmx, __shfl_xor(kmx, m));
    }
    if ((t & 63) == 0) { rmn[t >> 6] = kmn; rmx[t >> 6] = kmx; }
    if (t < RPB) cur[t] = 0;  // temp hist (same barrier covers this)
    __syncthreads();
    if (t == 0) {
#pragma unroll
        for (int w = 1; w < 8; ++w) {
            kmn = min(kmn, rmn[w]);
            kmx = max(kmx, rmx[w]);
        }
        const float mn = dec_f(kmn);
        const float mx = dec_f(kmx);
        s_mn = mn;
        s_inv = 1.0f / (mx - mn);
    }
    // pass 1: histogram (t0 finished its reduce before reaching the barrier)
    for (int i = t; i < cnt; i += 512) atomicAdd(&cur[eb[i].x >> 16], 1);
    __syncthreads();
    if (t == 0) {
        int run = 0;
#pragma unroll
        for (int r = 0; r < RPB; ++r) { off[r] = run; run += cur[r]; }
        off[RPB] = run;
    }
    __syncthreads();
    if (t < RPB) cur[t] = off[t];
    __syncthreads();
    const float mn = s_mn;
    const float inv = s_inv;
    // pass 2: counting-sort scatter (exp computed once per edge)
    for (int i = t; i < cnt; i += 512) {
        const uint2 e = eb[i];
        const int lr = (int)(e.x >> 16);
        const int p = atomicAdd(&cur[lr], 1);
        if (p < CAP) {
            scol[p] = (unsigned short)(e.x & 0xFFFFu);
            swt[p] = __expf((__int_as_float(e.y) - mn) * inv);
        }
    }
    __syncthreads();

    // row processing: 32 processors x 16 lanes, 2 dims/lane, 4-way unroll
    const int proc = t >> 4;  // 0..31
    const int d2 = t & 15;    // dims [2*d2, 2*d2+1]
    const unsigned* Xp32 = (const unsigned*)Xpb;
    for (int lr = proc; lr < RPB; lr += 32) {
        const int s = off[lr];
        const int e2 = off[lr + 1];
        float pa0 = 0.f, pa1 = 0.f, pa2 = 0.f, pa3 = 0.f;
        float pb0 = 0.f, pb1 = 0.f, pb2 = 0.f, pb3 = 0.f;
        float w0s = 0.f, w1s = 0.f, w2s = 0.f, w3s = 0.f;
        int i = s;
        for (; i + 3 < e2; i += 4) {
            const int c0 = scol[i];
            const int c1 = scol[i + 1];
            const int c2 = scol[i + 2];
            const int c3 = scol[i + 3];
            const float w0 = swt[i];
            const float w1 = swt[i + 1];
            const float w2 = swt[i + 2];
            const float w3 = swt[i + 3];
            const unsigned u0 = Xp32[(size_t)c0 * 16 + d2];
            const unsigned u1 = Xp32[(size_t)c1 * 16 + d2];
            const unsigned u2 = Xp32[(size_t)c2 * 16 + d2];
            const unsigned u3 = Xp32[(size_t)c3 * 16 + d2];
            pa0 += w0 * bf2f((unsigned short)(u0 & 0xFFFFu));
            pb0 += w0 * bf2f((unsigned short)(u0 >> 16));
            pa1 += w1 * bf2f((unsigned short)(u1 & 0xFFFFu));
            pb1 += w1 * bf2f((unsigned short)(u1 >> 16));
            pa2 += w2 * bf2f((unsigned short)(u2 & 0xFFFFu));
            pb2 += w2 * bf2f((unsigned short)(u2 >> 16));
            pa3 += w3 * bf2f((unsigned short)(u3 & 0xFFFFu));
            pb3 += w3 * bf2f((unsigned short)(u3 >> 16));
            w0s += w0; w1s += w1; w2s += w2; w3s += w3;
        }
        for (; i < e2; ++i) {
            const float w = swt[i];
            const unsigned u = Xp32[(size_t)scol[i] * 16 + d2];
            pa0 += w * bf2f((unsigned short)(u & 0xFFFFu));
            pb0 += w * bf2f((unsigned short)(u >> 16));
            w0s += w;
        }
        const int r = b * RPB + lr;
        if (r < N_NODES) {
            const float ws = w0s + w1s + w2s + w3s;
            float2 o;
            o.x = (pa0 + pa1 + pa2 + pa3) / ws;
            o.y = (pb0 + pb1 + pb2 + pb3) / ws;
            ((float2*)out)[(size_t)r * 16 + d2] = o;
        }
    }
}

extern "C" void kernel_launch(void* const* d_in, const int* in_sizes, int n_in,
                              void* d_out, int out_size, void* d_ws, size_t ws_size,
                              hipStream_t stream) {
    const float* X  = (const float*)d_in[0];
    const float* W  = (const float*)d_in[1];
    const float* a0 = (const float*)d_in[2];
    const float* a1 = (const float*)d_in[3];
    const int* row  = (const int*)d_in[4];
    const int* col  = (const int*)d_in[5];
    float* out = (float*)d_out;

    // Workspace layout (4B units):
    // [pad: 64][gcount padded: NBP*GST = 16384][mm: 3200]
    // [s0: 50048][s1: 50048][Xpb: 800000 u32][gEdges: NB*CAP uint2] ~21 MB
    float* ws = (float*)d_ws;
    int*   gcount = (int*)ws + 64;
    int2*  mm = (int2*)((int*)ws + 64 + NBP * GST);
    float* s0 = ws + 64 + NBP * GST + 3200;
    float* s1 = s0 + 50048;
    unsigned short* Xpb = (unsigned short*)(s1 + 50048);
    uint2* gEdges = (uint2*)(s1 + 50048 + 800000);

    k_gemm<<<NXB, 256, 0, stream>>>(X, W, a0, a1, Xpb, s0, s1, gcount);
    k_edge<<<NEB, 256, 0, stream>>>(row, col, s0, s1, gcount, mm, gEdges);
    k_bucket<<<NB, 512, 0, stream>>>(gcount, gEdges, Xpb, mm, out);
}

// Round 6
// 150.837 us; speedup vs baseline: 1.2729x; 1.1817x over previous
//
#include <hip/hip_runtime.h>
#include <hip/hip_bf16.h>
#include <math.h>

#define N_NODES 50000
#define N_EDGES 1600000
#define D_IN 128
#define D_OUT 32
#define ALPHA 0.2f

#define NB   256     // coarse buckets (density lever: EB/NB = 16 rec/bkt/blk)
#define RPB  196     // rows per bucket (256*196 = 50176 >= 50000)
#define CAP  8192    // record slots per bucket (mean ~6250, +24 sigma)
#define HRPB 49      // rows per quarter-bucket (k_bucket granularity)
#define CAPH 2048    // LDS-staged slots per quarter (mean ~1568, +12 sigma)
#define GST  16      // gcount stride in ints: one counter per 64B line
#define PT   16      // edges per thread in edge kernel
#define PBK  256     // edge kernel block size
#define EB   (PT * PBK)                     // 4096 edges per edge-block
#define NEB  ((N_EDGES + EB - 1) / EB)      // 391 edge blocks
#define XNPB 32      // nodes per GEMM block
#define NXB  ((N_NODES + XNPB - 1) / XNPB)  // 1563 GEMM blocks
#define XLS  33      // padded X-tile stride in float4 (bank-conflict fix)

// Monotone float<->int key (involution). Works with signed min/max.
__device__ __forceinline__ int enc_f(float x) {
    int i = __float_as_int(x);
    return i >= 0 ? i : (i ^ 0x7fffffff);
}
__device__ __forceinline__ float dec_f(int k) {
    return __int_as_float(k >= 0 ? k : (k ^ 0x7fffffff));
}
__device__ __forceinline__ unsigned short f2bf(float x) {
    __hip_bfloat16 h = __float2bfloat16(x);
    return *(unsigned short*)&h;
}
__device__ __forceinline__ float bf2f(unsigned short u) {
    return __uint_as_float((unsigned)u << 16);
}

// K1: GEMM X@W -> Xpb (bf16) with s0/s1 epilogue (s0=(X@W).a0 from the f32
// row already in registers). Single X pass. Padded-stride LDS X tile
// (conflict-free). Block 0 zeroes the padded gcount array (harness poisons
// the workspace every iteration, so this init is required).
__global__ __launch_bounds__(256) void k_gemm(const float* __restrict__ X,
                                              const float* __restrict__ W,
                                              const float* __restrict__ a0,
                                              const float* __restrict__ a1,
                                              unsigned short* __restrict__ Xpb,
                                              float* __restrict__ s0,
                                              float* __restrict__ s1,
                                              int* __restrict__ gcount) {
    __shared__ float4 Wl4[1024];        // 16 KB
    __shared__ float4 Xl4[XNPB * XLS];  // 16.9 KB (padded)
    const int tid = threadIdx.x;
    if (blockIdx.x == 0) {
        int4* g4 = (int4*)gcount;
#pragma unroll
        for (int i = 0; i < NB * GST / 4 / 256; ++i)
            g4[tid + 256 * i] = make_int4(0, 0, 0, 0);
    }
    const int node0 = blockIdx.x * XNPB;
    {
        const float4* W4 = (const float4*)W;
#pragma unroll
        for (int i = 0; i < 4; ++i) Wl4[tid + 256 * i] = W4[tid + 256 * i];
        const float4* X4 = (const float4*)X + (size_t)node0 * (D_IN / 4);
        const int lim = (min(XNPB, N_NODES - node0)) * (D_IN / 4);
#pragma unroll
        for (int i = 0; i < 4; ++i) {
            const int idx = tid + 256 * i;
            const float4 v = (idx < lim) ? X4[idx]
                                         : make_float4(0.f, 0.f, 0.f, 0.f);
            Xl4[(idx >> 5) * XLS + (idx & 31)] = v;
        }
    }
    __syncthreads();
    const int g = tid >> 3;  // node within block (0..31)
    const int l = tid & 7;   // lane -> dims [4l, 4l+4)
    const int node = node0 + g;
    const float4* xr = &Xl4[g * XLS];
    float ax = 0.f, ay = 0.f, az = 0.f, aw = 0.f;
#pragma unroll 4
    for (int kk = 0; kk < D_IN / 4; ++kk) {
        const float4 xv = xr[kk];
        const float4 w0 = Wl4[(4 * kk + 0) * 8 + l];
        const float4 w1 = Wl4[(4 * kk + 1) * 8 + l];
        const float4 w2 = Wl4[(4 * kk + 2) * 8 + l];
        const float4 w3 = Wl4[(4 * kk + 3) * 8 + l];
        ax += xv.x * w0.x + xv.y * w1.x + xv.z * w2.x + xv.w * w3.x;
        ay += xv.x * w0.y + xv.y * w1.y + xv.z * w2.y + xv.w * w3.y;
        az += xv.x * w0.z + xv.y * w1.z + xv.z * w2.z + xv.w * w3.z;
        aw += xv.x * w0.w + xv.y * w1.w + xv.z * w2.w + xv.w * w3.w;
    }
    if (node < N_NODES) {
        uint2 pk;
        pk.x = ((unsigned)f2bf(ay) << 16) | f2bf(ax);
        pk.y = ((unsigned)f2bf(aw) << 16) | f2bf(az);
        ((uint2*)Xpb)[(size_t)node * 8 + l] = pk;
        // score epilogue: dot f32 Xp row with a0/a1, reduce over 8 lanes
        const float4 av0 = ((const float4*)a0)[l];
        const float4 av1 = ((const float4*)a1)[l];
        float v0 = ax * av0.x + ay * av0.y + az * av0.z + aw * av0.w;
        float v1 = ax * av1.x + ay * av1.y + az * av1.z + aw * av1.w;
#pragma unroll
        for (int m = 4; m >= 1; m >>= 1) {
            v0 += __shfl_xor(v0, m);
            v1 += __shfl_xor(v1, m);
        }
        if (l == 0) { s0[node] = v0; s1[node] = v1; }
    }
}

// K2: edge pass v5 — DENSITY design. Empirical law across R0/R1/R4/R5:
// k_edge time tracks records-per-bucket-per-block (line-fill density of
// the gEdges scatter). 8/bkt -> 44us, 2 -> 46, 1 -> 66, 0 -> 84. Here:
// NB=256, EB=4096 -> density 16 (2x the best measured point), and global
// claims drop to 391x256 = 100K (R5 had 1M). Two-level LDS allocation
// (hist -> one global claim per touched bucket -> LDS-cursor scatter),
// record = (b:8|lr:8|col:16, att). min/max -> private mm[bid] slot.
__global__ __launch_bounds__(256) void k_edge(const int* __restrict__ row,
                                              const int* __restrict__ col,
                                              const float* __restrict__ s0,
                                              const float* __restrict__ s1,
                                              int* __restrict__ gcount,
                                              int2* __restrict__ mm,
                                              uint2* __restrict__ gEdges) {
    __shared__ int hist[NB];   // 1 KB
    __shared__ int lcur[NB];   // 1 KB
    __shared__ int smn[4], smx[4];
    const int tid = threadIdx.x;
    if (tid < NB) hist[tid] = 0;
    __syncthreads();
    const int base = blockIdx.x * EB;
    unsigned px[PT];  // (b:8 | lr:8 | col:16)
    float    fa[PT];  // leaky-relu'd score
    int cnt = 0;
    int kmin = 0x7fffffff, kmax = 0x80000000;
    if (base + EB <= N_EDGES) {   // full block: int4 vector loads
#pragma unroll
        for (int i = 0; i < PT / 4; ++i) {
            const int4 r4 = ((const int4*)(row + base))[tid + i * PBK];
            const int4 c4 = ((const int4*)(col + base))[tid + i * PBK];
            const int rr[4] = {r4.x, r4.y, r4.z, r4.w};
            const int cc[4] = {c4.x, c4.y, c4.z, c4.w};
#pragma unroll
            for (int j = 0; j < 4; ++j) {
                const int r = rr[j];
                const int c = cc[j];
                float a = s0[r] + s1[c];
                a = a > 0.f ? a : ALPHA * a;
                const int k = enc_f(a);
                kmin = min(kmin, k);
                kmax = max(kmax, k);
                const unsigned b = (unsigned)r / RPB;
                const unsigned lr = (unsigned)r - b * RPB;
                px[cnt] = (b << 24) | (lr << 16) | (unsigned)c;
                fa[cnt] = a;
                ++cnt;
                atomicAdd(&hist[b], 1);
            }
        }
    } else {                      // tail block: scalar guarded
#pragma unroll
        for (int i = 0; i < PT; ++i) {
            const int e = base + i * PBK + tid;
            if (e >= N_EDGES) break;
            const int r = row[e];
            const int c = col[e];
            float a = s0[r] + s1[c];
            a = a > 0.f ? a : ALPHA * a;
            const int k = enc_f(a);
            kmin = min(kmin, k);
            kmax = max(kmax, k);
            const unsigned b = (unsigned)r / RPB;
            const unsigned lr = (unsigned)r - b * RPB;
            px[cnt] = (b << 24) | (lr << 16) | (unsigned)c;
            fa[cnt] = a;
            ++cnt;
            atomicAdd(&hist[b], 1);
        }
    }
    __syncthreads();
    // merge: one contiguous global range per touched bucket (<=256 claims)
    if (tid < NB) {
        const int h = hist[tid];
        lcur[tid] = h > 0 ? atomicAdd(&gcount[tid << 4], h) : 0;
    }
    __syncthreads();
    // scatter: LDS cursor gives each record a mostly-sequential slot;
    // 16 records/bucket/block fill gEdges lines densely (write-amp fix)
    for (int j = 0; j < cnt; ++j) {
        const unsigned p = px[j];
        const unsigned b = p >> 24;
        const int pos = atomicAdd(&lcur[b], 1);
        if (pos < CAP)
            gEdges[(size_t)b * CAP + pos] =
                make_uint2(p, (unsigned)__float_as_int(fa[j]));
    }
    // epilogue: block min/max -> private slot (no contended atomics)
#pragma unroll
    for (int m = 32; m >= 1; m >>= 1) {
        kmin = min(kmin, __shfl_xor(kmin, m));
        kmax = max(kmax, __shfl_xor(kmax, m));
    }
    const int wave = tid >> 6;
    if ((tid & 63) == 0) { smn[wave] = kmin; smx[wave] = kmax; }
    __syncthreads();
    if (tid == 0) {
#pragma unroll
        for (int w = 1; w < 4; ++w) {
            kmin = min(kmin, smn[w]);
            kmax = max(kmax, smx[w]);
        }
        mm[blockIdx.x] = make_int2(kmin, kmax);
    }
}

// K3: one 512-thread block per QUARTER-bucket (1024 blocks, 49 rows each,
// ~12.5 KB LDS). Scans its coarse bucket's ~6250 records and filters by
// lr range (4x scan vs fine buckets — the price of k_edge's density win;
// ~13 extra iterations/block, sequential L2-hot reads).
// prologue: reduce the 391-entry per-edge-block minmax table;
// pass 1:   LDS histogram of this quarter's rows (49 bins);
// pass 2:   counting-sort scatter {col:u16, exp(minmaxnorm(score))};
// rows:     32 row-processors x 16 lanes (2 bf16 dims per lane via one u32
//           load), 4-way unrolled register accumulators, float2 out.
__global__ __launch_bounds__(512, 8) void k_bucket(const int* __restrict__ gcount,
                                                   const uint2* __restrict__ gEdges,
                                                   const unsigned short* __restrict__ Xpb,
                                                   const int2* __restrict__ mm,
                                                   float* __restrict__ out) {
    __shared__ unsigned short scol[CAPH]; // 4 KB
    __shared__ float swt[CAPH];           // 8 KB
    __shared__ int off[HRPB + 1];
    __shared__ int cur[HRPB];
    __shared__ int rmn[8], rmx[8];
    __shared__ float s_mn, s_inv;
    const int bid = blockIdx.x;
    const int b = bid >> 2;              // coarse bucket
    const int lo = (bid & 3) * HRPB;     // quarter's row range [lo, lo+49)
    const int t = threadIdx.x;
    const int cnt = min(gcount[b << 4], CAP);   // padded gcount
    const uint2* eb = gEdges + (size_t)b * CAP;

    // prologue: global min/max from the per-edge-block table
    int kmn = 0x7fffffff, kmx = 0x80000000;
    for (int i = t; i < NEB; i += 512) {
        const int2 v = mm[i];
        kmn = min(kmn, v.x);
        kmx = max(kmx, v.y);
    }
#pragma unroll
    for (int m = 32; m >= 1; m >>= 1) {
        kmn = min(kmn, __shfl_xor(kmn, m));
        kmx = max(kmx, __shfl_xor(kmx, m));
    }
    if ((t & 63) == 0) { rmn[t >> 6] = kmn; rmx[t >> 6] = kmx; }
    if (t < HRPB) cur[t] = 0;  // temp hist (same barrier covers this)
    __syncthreads();
    if (t == 0) {
#pragma unroll
        for (int w = 1; w < 8; ++w) {
            kmn = min(kmn, rmn[w]);
            kmx = max(kmx, rmx[w]);
        }
        const float mn = dec_f(kmn);
        const float mx = dec_f(kmx);
        s_mn = mn;
        s_inv = 1.0f / (mx - mn);
    }
    // pass 1: histogram of this quarter's rows
    for (int i = t; i < cnt; i += 512) {
        const int lrl = (int)((eb[i].x >> 16) & 0xFFu) - lo;
        if ((unsigned)lrl < (unsigned)HRPB) atomicAdd(&cur[lrl], 1);
    }
    __syncthreads();
    if (t == 0) {
        int run = 0;
#pragma unroll
        for (int r = 0; r < HRPB; ++r) { off[r] = run; run += cur[r]; }
        off[HRPB] = run;
    }
    __syncthreads();
    if (t < HRPB) cur[t] = off[t];
    __syncthreads();
    const float mn = s_mn;
    const float inv = s_inv;
    // pass 2: counting-sort scatter (exp computed once per edge)
    for (int i = t; i < cnt; i += 512) {
        const uint2 e = eb[i];
        const int lrl = (int)((e.x >> 16) & 0xFFu) - lo;
        if ((unsigned)lrl < (unsigned)HRPB) {
            const int p = atomicAdd(&cur[lrl], 1);
            if (p < CAPH) {
                scol[p] = (unsigned short)(e.x & 0xFFFFu);
                swt[p] = __expf((__int_as_float(e.y) - mn) * inv);
            }
        }
    }
    __syncthreads();

    // row processing: 32 processors x 16 lanes, 2 dims/lane, 4-way unroll
    const int proc = t >> 4;  // 0..31
    const int d2 = t & 15;    // dims [2*d2, 2*d2+1]
    const unsigned* Xp32 = (const unsigned*)Xpb;
    for (int lr = proc; lr < HRPB; lr += 32) {
        const int s = off[lr];
        const int e2 = min(off[lr + 1], CAPH);
        float pa0 = 0.f, pa1 = 0.f, pa2 = 0.f, pa3 = 0.f;
        float pb0 = 0.f, pb1 = 0.f, pb2 = 0.f, pb3 = 0.f;
        float w0s = 0.f, w1s = 0.f, w2s = 0.f, w3s = 0.f;
        int i = s;
        for (; i + 3 < e2; i += 4) {
            const int c0 = scol[i];
            const int c1 = scol[i + 1];
            const int c2 = scol[i + 2];
            const int c3 = scol[i + 3];
            const float w0 = swt[i];
            const float w1 = swt[i + 1];
            const float w2 = swt[i + 2];
            const float w3 = swt[i + 3];
            const unsigned u0 = Xp32[(size_t)c0 * 16 + d2];
            const unsigned u1 = Xp32[(size_t)c1 * 16 + d2];
            const unsigned u2 = Xp32[(size_t)c2 * 16 + d2];
            const unsigned u3 = Xp32[(size_t)c3 * 16 + d2];
            pa0 += w0 * bf2f((unsigned short)(u0 & 0xFFFFu));
            pb0 += w0 * bf2f((unsigned short)(u0 >> 16));
            pa1 += w1 * bf2f((unsigned short)(u1 & 0xFFFFu));
            pb1 += w1 * bf2f((unsigned short)(u1 >> 16));
            pa2 += w2 * bf2f((unsigned short)(u2 & 0xFFFFu));
            pb2 += w2 * bf2f((unsigned short)(u2 >> 16));
            pa3 += w3 * bf2f((unsigned short)(u3 & 0xFFFFu));
            pb3 += w3 * bf2f((unsigned short)(u3 >> 16));
            w0s += w0; w1s += w1; w2s += w2; w3s += w3;
        }
        for (; i < e2; ++i) {
            const float w = swt[i];
            const unsigned u = Xp32[(size_t)scol[i] * 16 + d2];
            pa0 += w * bf2f((unsigned short)(u & 0xFFFFu));
            pb0 += w * bf2f((unsigned short)(u >> 16));
            w0s += w;
        }
        const int r = b * RPB + lo + lr;
        if (r < N_NODES) {
            const float ws = w0s + w1s + w2s + w3s;
            float2 o;
            o.x = (pa0 + pa1 + pa2 + pa3) / ws;
            o.y = (pb0 + pb1 + pb2 + pb3) / ws;
            ((float2*)out)[(size_t)r * 16 + d2] = o;
        }
    }
}

extern "C" void kernel_launch(void* const* d_in, const int* in_sizes, int n_in,
                              void* d_out, int out_size, void* d_ws, size_t ws_size,
                              hipStream_t stream) {
    const float* X  = (const float*)d_in[0];
    const float* W  = (const float*)d_in[1];
    const float* a0 = (const float*)d_in[2];
    const float* a1 = (const float*)d_in[3];
    const int* row  = (const int*)d_in[4];
    const int* col  = (const int*)d_in[5];
    float* out = (float*)d_out;

    // Workspace layout (4B units):
    // [pad: 64][gcount padded: NB*GST = 4096][mm: 1024]
    // [s0: 50048][s1: 50048][Xpb: 800000 u32][gEdges: NB*CAP uint2] ~20.4 MB
    float* ws = (float*)d_ws;
    int*   gcount = (int*)ws + 64;
    int2*  mm = (int2*)((int*)ws + 64 + NB * GST);
    float* s0 = ws + 64 + NB * GST + 1024;
    float* s1 = s0 + 50048;
    unsigned short* Xpb = (unsigned short*)(s1 + 50048);
    uint2* gEdges = (uint2*)(s1 + 50048 + 800000);

    k_gemm<<<NXB, 256, 0, stream>>>(X, W, a0, a1, Xpb, s0, s1, gcount);
    k_edge<<<NEB, 256, 0, stream>>>(row, col, s0, s1, gcount, mm, gEdges);
    k_bucket<<<NB * 4, 512, 0, stream>>>(gcount, gEdges, Xpb, mm, out);
}

// Round 7
// 144.198 us; speedup vs baseline: 1.3315x; 1.0460x over previous
//
#include <hip/hip_runtime.h>
#include <hip/hip_bf16.h>
#include <math.h>

#define N_NODES 50000
#define N_EDGES 1600000
#define D_IN 128
#define D_OUT 32
#define ALPHA 0.2f

#define NB   256     // coarse buckets (density: EB/NB = 16 rec/bkt/blk)
#define RPB  196     // rows per bucket (256*196 = 50176 >= 50000)
#define CAP  8192    // record slots per bucket (mean ~6250, +24 sigma)
#define GST  16      // gcount stride in ints: one counter per 64B line
#define PT   16      // edges per thread in edge kernel
#define PBK  256     // edge kernel block size
#define EB   (PT * PBK)                     // 4096 edges per edge-block
#define NEB  ((N_EDGES + EB - 1) / EB)      // 391 edge blocks
#define XNPB 32      // nodes per GEMM block
#define NXB  ((N_NODES + XNPB - 1) / XNPB)  // 1563 GEMM blocks
#define XLS  33      // padded X-tile stride in float4 (bank-conflict fix)

// Monotone float<->int key (involution). Works with signed min/max.
__device__ __forceinline__ int enc_f(float x) {
    int i = __float_as_int(x);
    return i >= 0 ? i : (i ^ 0x7fffffff);
}
__device__ __forceinline__ float dec_f(int k) {
    return __int_as_float(k >= 0 ? k : (k ^ 0x7fffffff));
}
__device__ __forceinline__ unsigned short f2bf(float x) {
    __hip_bfloat16 h = __float2bfloat16(x);
    return *(unsigned short*)&h;
}
__device__ __forceinline__ float bf2f(unsigned short u) {
    return __uint_as_float((unsigned)u << 16);
}

// K1: GEMM X@W -> Xpb (bf16) with s0/s1 epilogue (s0=(X@W).a0 from the f32
// row already in registers). Single X pass. Padded-stride LDS X tile
// (conflict-free). Block 0 zeroes the padded gcount array (harness poisons
// the workspace every iteration, so this init is required).
__global__ __launch_bounds__(256) void k_gemm(const float* __restrict__ X,
                                              const float* __restrict__ W,
                                              const float* __restrict__ a0,
                                              const float* __restrict__ a1,
                                              unsigned short* __restrict__ Xpb,
                                              float* __restrict__ s0,
                                              float* __restrict__ s1,
                                              int* __restrict__ gcount) {
    __shared__ float4 Wl4[1024];        // 16 KB
    __shared__ float4 Xl4[XNPB * XLS];  // 16.9 KB (padded)
    const int tid = threadIdx.x;
    if (blockIdx.x == 0) {
        int4* g4 = (int4*)gcount;
#pragma unroll
        for (int i = 0; i < NB * GST / 4 / 256; ++i)
            g4[tid + 256 * i] = make_int4(0, 0, 0, 0);
    }
    const int node0 = blockIdx.x * XNPB;
    {
        const float4* W4 = (const float4*)W;
#pragma unroll
        for (int i = 0; i < 4; ++i) Wl4[tid + 256 * i] = W4[tid + 256 * i];
        const float4* X4 = (const float4*)X + (size_t)node0 * (D_IN / 4);
        const int lim = (min(XNPB, N_NODES - node0)) * (D_IN / 4);
#pragma unroll
        for (int i = 0; i < 4; ++i) {
            const int idx = tid + 256 * i;
            const float4 v = (idx < lim) ? X4[idx]
                                         : make_float4(0.f, 0.f, 0.f, 0.f);
            Xl4[(idx >> 5) * XLS + (idx & 31)] = v;
        }
    }
    __syncthreads();
    const int g = tid >> 3;  // node within block (0..31)
    const int l = tid & 7;   // lane -> dims [4l, 4l+4)
    const int node = node0 + g;
    const float4* xr = &Xl4[g * XLS];
    float ax = 0.f, ay = 0.f, az = 0.f, aw = 0.f;
#pragma unroll 4
    for (int kk = 0; kk < D_IN / 4; ++kk) {
        const float4 xv = xr[kk];
        const float4 w0 = Wl4[(4 * kk + 0) * 8 + l];
        const float4 w1 = Wl4[(4 * kk + 1) * 8 + l];
        const float4 w2 = Wl4[(4 * kk + 2) * 8 + l];
        const float4 w3 = Wl4[(4 * kk + 3) * 8 + l];
        ax += xv.x * w0.x + xv.y * w1.x + xv.z * w2.x + xv.w * w3.x;
        ay += xv.x * w0.y + xv.y * w1.y + xv.z * w2.y + xv.w * w3.y;
        az += xv.x * w0.z + xv.y * w1.z + xv.z * w2.z + xv.w * w3.z;
        aw += xv.x * w0.w + xv.y * w1.w + xv.z * w2.w + xv.w * w3.w;
    }
    if (node < N_NODES) {
        uint2 pk;
        pk.x = ((unsigned)f2bf(ay) << 16) | f2bf(ax);
        pk.y = ((unsigned)f2bf(aw) << 16) | f2bf(az);
        ((uint2*)Xpb)[(size_t)node * 8 + l] = pk;
        // score epilogue: dot f32 Xp row with a0/a1, reduce over 8 lanes
        const float4 av0 = ((const float4*)a0)[l];
        const float4 av1 = ((const float4*)a1)[l];
        float v0 = ax * av0.x + ay * av0.y + az * av0.z + aw * av0.w;
        float v1 = ax * av1.x + ay * av1.y + az * av1.z + aw * av1.w;
#pragma unroll
        for (int m = 4; m >= 1; m >>= 1) {
            v0 += __shfl_xor(v0, m);
            v1 += __shfl_xor(v1, m);
        }
        if (l == 0) { s0[node] = v0; s1[node] = v1; }
    }
}

// K2: edge pass v6 — LDS-staged counting sort + COALESCED write-out.
// R6 (density 16, direct scatter) proved the density law but still issued
// 16 independent scattered 8B stores per thread. Here all 4096 records are
// counting-sorted into a 32KB LDS staging buffer (local prefix over 256
// bins), then copied out as contiguous per-bucket runs: consecutive
// threads -> consecutive addresses -> full-line burst stores.
// Global claims stay at one per touched bucket (<=256/block).
// min/max -> private mm[bid] slot (k_bucket reduces the table).
__global__ __launch_bounds__(256) void k_edge(const int* __restrict__ row,
                                              const int* __restrict__ col,
                                              const float* __restrict__ s0,
                                              const float* __restrict__ s1,
                                              int* __restrict__ gcount,
                                              int2* __restrict__ mm,
                                              uint2* __restrict__ gEdges) {
    __shared__ uint2 rec[EB];       // 32 KB staging
    __shared__ int hist[NB];        // 1 KB
    __shared__ int off[NB + 1];     // 1 KB: staging layout
    __shared__ int lcur[NB];        // 1 KB: staging cursors
    __shared__ int gbase[NB];       // 1 KB: claimed global bases
    __shared__ int smn[4], smx[4];
    const int tid = threadIdx.x;
    if (tid < NB) hist[tid] = 0;
    __syncthreads();
    const int base = blockIdx.x * EB;
    unsigned px[PT];  // (b:8 | lr:8 | col:16)
    float    fa[PT];  // leaky-relu'd score
    int cnt = 0;
    int kmin = 0x7fffffff, kmax = 0x80000000;
    if (base + EB <= N_EDGES) {   // full block: int4 vector loads
#pragma unroll
        for (int i = 0; i < PT / 4; ++i) {
            const int4 r4 = ((const int4*)(row + base))[tid + i * PBK];
            const int4 c4 = ((const int4*)(col + base))[tid + i * PBK];
            const int rr[4] = {r4.x, r4.y, r4.z, r4.w};
            const int cc[4] = {c4.x, c4.y, c4.z, c4.w};
#pragma unroll
            for (int j = 0; j < 4; ++j) {
                const int r = rr[j];
                const int c = cc[j];
                float a = s0[r] + s1[c];
                a = a > 0.f ? a : ALPHA * a;
                const int k = enc_f(a);
                kmin = min(kmin, k);
                kmax = max(kmax, k);
                const unsigned b = (unsigned)r / RPB;
                const unsigned lr = (unsigned)r - b * RPB;
                px[cnt] = (b << 24) | (lr << 16) | (unsigned)c;
                fa[cnt] = a;
                ++cnt;
                atomicAdd(&hist[b], 1);
            }
        }
    } else {                      // tail block: scalar guarded
#pragma unroll
        for (int i = 0; i < PT; ++i) {
            const int e = base + i * PBK + tid;
            if (e >= N_EDGES) break;
            const int r = row[e];
            const int c = col[e];
            float a = s0[r] + s1[c];
            a = a > 0.f ? a : ALPHA * a;
            const int k = enc_f(a);
            kmin = min(kmin, k);
            kmax = max(kmax, k);
            const unsigned b = (unsigned)r / RPB;
            const unsigned lr = (unsigned)r - b * RPB;
            px[cnt] = (b << 24) | (lr << 16) | (unsigned)c;
            fa[cnt] = a;
            ++cnt;
            atomicAdd(&hist[b], 1);
        }
    }
    __syncthreads();
    // claim one contiguous global range per touched bucket; local prefix
    if (tid < NB) {
        const int h = hist[tid];
        gbase[tid] = h > 0 ? atomicAdd(&gcount[tid << 4], h) : 0;
    }
    if (tid == 0) {
        int run = 0;
        for (int i = 0; i < NB; ++i) { off[i] = run; run += hist[i]; }
        off[NB] = run;
    }
    __syncthreads();
    if (tid < NB) lcur[tid] = off[tid];
    __syncthreads();
    // counting-sort scatter into LDS staging (bucket-contiguous)
    for (int j = 0; j < cnt; ++j) {
        const unsigned b = px[j] >> 24;
        const int p = atomicAdd(&lcur[b], 1);
        rec[p] = make_uint2(px[j], (unsigned)__float_as_int(fa[j]));
    }
    __syncthreads();
    // coalesced copy-out: consecutive i -> same-bucket run -> burst stores
    const int total = off[NB];
    for (int i = tid; i < total; i += PBK) {
        const uint2 e = rec[i];
        const unsigned b = e.x >> 24;
        const int pos = gbase[b] + (i - off[b]);
        if (pos < CAP) gEdges[(size_t)b * CAP + pos] = e;
    }
    // epilogue: block min/max -> private slot (no contended atomics)
#pragma unroll
    for (int m = 32; m >= 1; m >>= 1) {
        kmin = min(kmin, __shfl_xor(kmin, m));
        kmax = max(kmax, __shfl_xor(kmax, m));
    }
    const int wave = tid >> 6;
    if ((tid & 63) == 0) { smn[wave] = kmin; smx[wave] = kmax; }
    __syncthreads();
    if (tid == 0) {
#pragma unroll
        for (int w = 1; w < 4; ++w) {
            kmin = min(kmin, smn[w]);
            kmax = max(kmax, smx[w]);
        }
        mm[blockIdx.x] = make_int2(kmin, kmax);
    }
}

// K3: one 1024-thread block per FULL coarse bucket (256 blocks, ~51 KB LDS,
// 16 waves/CU). Single scan of the bucket's records (R6's quarter-blocks
// scanned everything 4x: 51 MB vs 12.8 MB).
// prologue: reduce the 391-entry per-edge-block minmax table;
// pass 1:   LDS histogram of the bucket's 196 rows;
// pass 2:   counting-sort scatter {col:u16, exp(minmaxnorm(score))};
// rows:     64 row-processors x 16 lanes (2 bf16 dims per lane via one u32
//           load), 4-way unrolled register accumulators, float2 out.
__global__ __launch_bounds__(1024, 1) void k_bucket(const int* __restrict__ gcount,
                                                    const uint2* __restrict__ gEdges,
                                                    const unsigned short* __restrict__ Xpb,
                                                    const int2* __restrict__ mm,
                                                    float* __restrict__ out) {
    __shared__ unsigned short scol[CAP]; // 16 KB
    __shared__ float swt[CAP];           // 32 KB
    __shared__ int off[RPB + 1];
    __shared__ int cur[RPB];
    __shared__ int rmn[16], rmx[16];
    __shared__ float s_mn, s_inv;
    const int b = blockIdx.x;
    const int t = threadIdx.x;
    const int cnt = min(gcount[b << 4], CAP);   // padded gcount
    const uint2* eb = gEdges + (size_t)b * CAP;

    // prologue: global min/max from the per-edge-block table
    int kmn = 0x7fffffff, kmx = 0x80000000;
    for (int i = t; i < NEB; i += 1024) {
        const int2 v = mm[i];
        kmn = min(kmn, v.x);
        kmx = max(kmx, v.y);
    }
#pragma unroll
    for (int m = 32; m >= 1; m >>= 1) {
        kmn = min(kmn, __shfl_xor(kmn, m));
        kmx = max(kmx, __shfl_xor(kmx, m));
    }
    if ((t & 63) == 0) { rmn[t >> 6] = kmn; rmx[t >> 6] = kmx; }
    if (t < RPB) cur[t] = 0;  // temp hist (same barrier covers this)
    __syncthreads();
    if (t == 0) {
#pragma unroll
        for (int w = 1; w < 16; ++w) {
            kmn = min(kmn, rmn[w]);
            kmx = max(kmx, rmx[w]);
        }
        const float mn = dec_f(kmn);
        const float mx = dec_f(kmx);
        s_mn = mn;
        s_inv = 1.0f / (mx - mn);
    }
    // pass 1: histogram of the bucket's rows
    for (int i = t; i < cnt; i += 1024)
        atomicAdd(&cur[(eb[i].x >> 16) & 0xFFu], 1);
    __syncthreads();
    if (t == 0) {
        int run = 0;
#pragma unroll
        for (int r = 0; r < RPB; ++r) { off[r] = run; run += cur[r]; }
        off[RPB] = run;
    }
    __syncthreads();
    if (t < RPB) cur[t] = off[t];
    __syncthreads();
    const float mn = s_mn;
    const float inv = s_inv;
    // pass 2: counting-sort scatter (exp computed once per edge)
    for (int i = t; i < cnt; i += 1024) {
        const uint2 e = eb[i];
        const int lr = (int)((e.x >> 16) & 0xFFu);
        const int p = atomicAdd(&cur[lr], 1);
        if (p < CAP) {
            scol[p] = (unsigned short)(e.x & 0xFFFFu);
            swt[p] = __expf((__int_as_float(e.y) - mn) * inv);
        }
    }
    __syncthreads();

    // row processing: 64 processors x 16 lanes, 2 dims/lane, 4-way unroll
    const int proc = t >> 4;  // 0..63
    const int d2 = t & 15;    // dims [2*d2, 2*d2+1]
    const unsigned* Xp32 = (const unsigned*)Xpb;
    for (int lr = proc; lr < RPB; lr += 64) {
        const int s = off[lr];
        const int e2 = off[lr + 1];
        float pa0 = 0.f, pa1 = 0.f, pa2 = 0.f, pa3 = 0.f;
        float pb0 = 0.f, pb1 = 0.f, pb2 = 0.f, pb3 = 0.f;
        float w0s = 0.f, w1s = 0.f, w2s = 0.f, w3s = 0.f;
        int i = s;
        for (; i + 3 < e2; i += 4) {
            const int c0 = scol[i];
            const int c1 = scol[i + 1];
            const int c2 = scol[i + 2];
            const int c3 = scol[i + 3];
            const float w0 = swt[i];
            const float w1 = swt[i + 1];
            const float w2 = swt[i + 2];
            const float w3 = swt[i + 3];
            const unsigned u0 = Xp32[(size_t)c0 * 16 + d2];
            const unsigned u1 = Xp32[(size_t)c1 * 16 + d2];
            const unsigned u2 = Xp32[(size_t)c2 * 16 + d2];
            const unsigned u3 = Xp32[(size_t)c3 * 16 + d2];
            pa0 += w0 * bf2f((unsigned short)(u0 & 0xFFFFu));
            pb0 += w0 * bf2f((unsigned short)(u0 >> 16));
            pa1 += w1 * bf2f((unsigned short)(u1 & 0xFFFFu));
            pb1 += w1 * bf2f((unsigned short)(u1 >> 16));
            pa2 += w2 * bf2f((unsigned short)(u2 & 0xFFFFu));
            pb2 += w2 * bf2f((unsigned short)(u2 >> 16));
            pa3 += w3 * bf2f((unsigned short)(u3 & 0xFFFFu));
            pb3 += w3 * bf2f((unsigned short)(u3 >> 16));
            w0s += w0; w1s += w1; w2s += w2; w3s += w3;
        }
        for (; i < e2; ++i) {
            const float w = swt[i];
            const unsigned u = Xp32[(size_t)scol[i] * 16 + d2];
            pa0 += w * bf2f((unsigned short)(u & 0xFFFFu));
            pb0 += w * bf2f((unsigned short)(u >> 16));
            w0s += w;
        }
        const int r = b * RPB + lr;
        if (r < N_NODES) {
            const float ws = w0s + w1s + w2s + w3s;
            float2 o;
            o.x = (pa0 + pa1 + pa2 + pa3) / ws;
            o.y = (pb0 + pb1 + pb2 + pb3) / ws;
            ((float2*)out)[(size_t)r * 16 + d2] = o;
        }
    }
}

extern "C" void kernel_launch(void* const* d_in, const int* in_sizes, int n_in,
                              void* d_out, int out_size, void* d_ws, size_t ws_size,
                              hipStream_t stream) {
    const float* X  = (const float*)d_in[0];
    const float* W  = (const float*)d_in[1];
    const float* a0 = (const float*)d_in[2];
    const float* a1 = (const float*)d_in[3];
    const int* row  = (const int*)d_in[4];
    const int* col  = (const int*)d_in[5];
    float* out = (float*)d_out;

    // Workspace layout (4B units):
    // [pad: 64][gcount padded: NB*GST = 4096][mm: 1024]
    // [s0: 50048][s1: 50048][Xpb: 800000 u32][gEdges: NB*CAP uint2] ~20.4 MB
    float* ws = (float*)d_ws;
    int*   gcount = (int*)ws + 64;
    int2*  mm = (int2*)((int*)ws + 64 + NB * GST);
    float* s0 = ws + 64 + NB * GST + 1024;
    float* s1 = s0 + 50048;
    unsigned short* Xpb = (unsigned short*)(s1 + 50048);
    uint2* gEdges = (uint2*)(s1 + 50048 + 800000);

    k_gemm<<<NXB, 256, 0, stream>>>(X, W, a0, a1, Xpb, s0, s1, gcount);
    k_edge<<<NEB, 256, 0, stream>>>(row, col, s0, s1, gcount, mm, gEdges);
    k_bucket<<<NB, 1024, 0, stream>>>(gcount, gEdges, Xpb, mm, out);
}

// Round 8
// 142.510 us; speedup vs baseline: 1.3473x; 1.0118x over previous
//
#include <hip/hip_runtime.h>
#include <hip/hip_bf16.h>
#include <math.h>

#define N_NODES 50000
#define N_EDGES 1600000
#define D_IN 128
#define D_OUT 32
#define ALPHA 0.2f

#define NB   256     // coarse buckets (density: EB/NB = 16 rec/bkt/blk)
#define RPB  196     // rows per bucket (256*196 = 50176 >= 50000)
#define CAP  8192    // record slots per bucket (mean ~6250, +24 sigma)
#define GST  16      // gcount stride in ints: one counter per 64B line
#define PT   16      // edges per thread in edge kernel
#define PBK  256     // edge kernel block size
#define EB   (PT * PBK)                     // 4096 edges per edge-block
#define NEB  ((N_EDGES + EB - 1) / EB)      // 391 edge blocks
#define XNPB 64      // nodes per GEMM block (2 nodes/thread: W-reuse lever)
#define NXB  ((N_NODES + XNPB - 1) / XNPB)  // 782 GEMM blocks
#define XLS  33      // padded X-tile stride in float4 (bank-conflict fix)

// Monotone float<->int key (involution). Works with signed min/max.
__device__ __forceinline__ int enc_f(float x) {
    int i = __float_as_int(x);
    return i >= 0 ? i : (i ^ 0x7fffffff);
}
__device__ __forceinline__ float dec_f(int k) {
    return __int_as_float(k >= 0 ? k : (k ^ 0x7fffffff));
}
__device__ __forceinline__ unsigned short f2bf(float x) {
    __hip_bfloat16 h = __float2bfloat16(x);
    return *(unsigned short*)&h;
}
__device__ __forceinline__ float bf2f(unsigned short u) {
    return __uint_as_float((unsigned)u << 16);
}

// K1: GEMM X@W -> Xpb (bf16) with s0/s1 epilogue, 2 NODES PER THREAD.
// R7 analysis: the kernel is LDS-read-bound and W reads are 4x X reads;
// amortizing the 4 W float4 reads over 2 X rows cuts LDS reads/node x0.6
// (per kk: 2 X + 4 W reads for 32 FMA4, vs 1 X + 4 W for 16).
// Padded stride 33 keeps both node rows conflict-free (1056 % 32 == 0).
// Block 0 zeroes the padded gcount array (harness re-poisons workspace).
__global__ __launch_bounds__(256) void k_gemm(const float* __restrict__ X,
                                              const float* __restrict__ W,
                                              const float* __restrict__ a0,
                                              const float* __restrict__ a1,
                                              unsigned short* __restrict__ Xpb,
                                              float* __restrict__ s0,
                                              float* __restrict__ s1,
                                              int* __restrict__ gcount) {
    __shared__ float4 Wl4[1024];        // 16 KB
    __shared__ float4 Xl4[XNPB * XLS];  // 33.8 KB (padded)
    const int tid = threadIdx.x;
    if (blockIdx.x == 0) {
        int4* g4 = (int4*)gcount;
#pragma unroll
        for (int i = 0; i < NB * GST / 4 / 256; ++i)
            g4[tid + 256 * i] = make_int4(0, 0, 0, 0);
    }
    const int node0 = blockIdx.x * XNPB;
    {
        const float4* W4 = (const float4*)W;
#pragma unroll
        for (int i = 0; i < 4; ++i) Wl4[tid + 256 * i] = W4[tid + 256 * i];
        const float4* X4 = (const float4*)X + (size_t)node0 * (D_IN / 4);
        const int lim = (min(XNPB, N_NODES - node0)) * (D_IN / 4);
#pragma unroll
        for (int i = 0; i < 8; ++i) {
            const int idx = tid + 256 * i;
            const float4 v = (idx < lim) ? X4[idx]
                                         : make_float4(0.f, 0.f, 0.f, 0.f);
            Xl4[(idx >> 5) * XLS + (idx & 31)] = v;
        }
    }
    __syncthreads();
    const int g = tid >> 3;  // node pair (0..31): nodes g and g+32
    const int l = tid & 7;   // lane -> dims [4l, 4l+4)
    const float4* xr0 = &Xl4[g * XLS];
    const float4* xr1 = &Xl4[(g + 32) * XLS];
    float axA = 0.f, ayA = 0.f, azA = 0.f, awA = 0.f;
    float axB = 0.f, ayB = 0.f, azB = 0.f, awB = 0.f;
#pragma unroll 4
    for (int kk = 0; kk < D_IN / 4; ++kk) {
        const float4 xa = xr0[kk];
        const float4 xb = xr1[kk];
        const float4 w0 = Wl4[(4 * kk + 0) * 8 + l];
        const float4 w1 = Wl4[(4 * kk + 1) * 8 + l];
        const float4 w2 = Wl4[(4 * kk + 2) * 8 + l];
        const float4 w3 = Wl4[(4 * kk + 3) * 8 + l];
        axA += xa.x * w0.x + xa.y * w1.x + xa.z * w2.x + xa.w * w3.x;
        ayA += xa.x * w0.y + xa.y * w1.y + xa.z * w2.y + xa.w * w3.y;
        azA += xa.x * w0.z + xa.y * w1.z + xa.z * w2.z + xa.w * w3.z;
        awA += xa.x * w0.w + xa.y * w1.w + xa.z * w2.w + xa.w * w3.w;
        axB += xb.x * w0.x + xb.y * w1.x + xb.z * w2.x + xb.w * w3.x;
        ayB += xb.x * w0.y + xb.y * w1.y + xb.z * w2.y + xb.w * w3.y;
        azB += xb.x * w0.z + xb.y * w1.z + xb.z * w2.z + xb.w * w3.z;
        awB += xb.x * w0.w + xb.y * w1.w + xb.z * w2.w + xb.w * w3.w;
    }
    const float4 av0 = ((const float4*)a0)[l];
    const float4 av1 = ((const float4*)a1)[l];
    {   // node A = node0 + g
        const int node = node0 + g;
        if (node < N_NODES) {
            uint2 pk;
            pk.x = ((unsigned)f2bf(ayA) << 16) | f2bf(axA);
            pk.y = ((unsigned)f2bf(awA) << 16) | f2bf(azA);
            ((uint2*)Xpb)[(size_t)node * 8 + l] = pk;
            float v0 = axA * av0.x + ayA * av0.y + azA * av0.z + awA * av0.w;
            float v1 = axA * av1.x + ayA * av1.y + azA * av1.z + awA * av1.w;
#pragma unroll
            for (int m = 4; m >= 1; m >>= 1) {
                v0 += __shfl_xor(v0, m);
                v1 += __shfl_xor(v1, m);
            }
            if (l == 0) { s0[node] = v0; s1[node] = v1; }
        }
    }
    {   // node B = node0 + g + 32
        const int node = node0 + g + 32;
        if (node < N_NODES) {
            uint2 pk;
            pk.x = ((unsigned)f2bf(ayB) << 16) | f2bf(axB);
            pk.y = ((unsigned)f2bf(awB) << 16) | f2bf(azB);
            ((uint2*)Xpb)[(size_t)node * 8 + l] = pk;
            float v0 = axB * av0.x + ayB * av0.y + azB * av0.z + awB * av0.w;
            float v1 = axB * av1.x + ayB * av1.y + azB * av1.z + awB * av1.w;
#pragma unroll
            for (int m = 4; m >= 1; m >>= 1) {
                v0 += __shfl_xor(v0, m);
                v1 += __shfl_xor(v1, m);
            }
            if (l == 0) { s0[node] = v0; s1[node] = v1; }
        }
    }
}

// K2: edge pass v7 — LDS-staged counting sort + coalesced write-out (R7,
// validated) with the serial thread-0 prefix replaced by a wave-level
// __shfl_up scan (the ~256-step dependent LDS loop was ~1us on each
// block's critical path). Global claims: one per touched bucket.
// min/max -> private mm[bid] slot (k_bucket reduces the table).
__global__ __launch_bounds__(256) void k_edge(const int* __restrict__ row,
                                              const int* __restrict__ col,
                                              const float* __restrict__ s0,
                                              const float* __restrict__ s1,
                                              int* __restrict__ gcount,
                                              int2* __restrict__ mm,
                                              uint2* __restrict__ gEdges) {
    __shared__ uint2 rec[EB];       // 32 KB staging
    __shared__ int hist[NB];        // 1 KB
    __shared__ int off[NB + 1];     // 1 KB: staging layout
    __shared__ int lcur[NB];        // 1 KB: staging cursors
    __shared__ int gbase[NB];       // 1 KB: claimed global bases
    __shared__ int wse[4];
    __shared__ int smn[4], smx[4];
    const int tid = threadIdx.x;
    if (tid < NB) hist[tid] = 0;
    __syncthreads();
    const int base = blockIdx.x * EB;
    unsigned px[PT];  // (b:8 | lr:8 | col:16)
    float    fa[PT];  // leaky-relu'd score
    int cnt = 0;
    int kmin = 0x7fffffff, kmax = 0x80000000;
    if (base + EB <= N_EDGES) {   // full block: int4 vector loads
#pragma unroll
        for (int i = 0; i < PT / 4; ++i) {
            const int4 r4 = ((const int4*)(row + base))[tid + i * PBK];
            const int4 c4 = ((const int4*)(col + base))[tid + i * PBK];
            const int rr[4] = {r4.x, r4.y, r4.z, r4.w};
            const int cc[4] = {c4.x, c4.y, c4.z, c4.w};
#pragma unroll
            for (int j = 0; j < 4; ++j) {
                const int r = rr[j];
                const int c = cc[j];
                float a = s0[r] + s1[c];
                a = a > 0.f ? a : ALPHA * a;
                const int k = enc_f(a);
                kmin = min(kmin, k);
                kmax = max(kmax, k);
                const unsigned b = (unsigned)r / RPB;
                const unsigned lr = (unsigned)r - b * RPB;
                px[cnt] = (b << 24) | (lr << 16) | (unsigned)c;
                fa[cnt] = a;
                ++cnt;
                atomicAdd(&hist[b], 1);
            }
        }
    } else {                      // tail block: scalar guarded
#pragma unroll
        for (int i = 0; i < PT; ++i) {
            const int e = base + i * PBK + tid;
            if (e >= N_EDGES) break;
            const int r = row[e];
            const int c = col[e];
            float a = s0[r] + s1[c];
            a = a > 0.f ? a : ALPHA * a;
            const int k = enc_f(a);
            kmin = min(kmin, k);
            kmax = max(kmax, k);
            const unsigned b = (unsigned)r / RPB;
            const unsigned lr = (unsigned)r - b * RPB;
            px[cnt] = (b << 24) | (lr << 16) | (unsigned)c;
            fa[cnt] = a;
            ++cnt;
            atomicAdd(&hist[b], 1);
        }
    }
    __syncthreads();
    // claim one contiguous global range per touched bucket (overlaps scan)
    const int h = hist[tid];
    gbase[tid] = h > 0 ? atomicAdd(&gcount[tid << 4], h) : 0;
    // parallel exclusive scan of hist -> off/lcur (wave shfl + 4-wave fix)
    {
        const int lane = tid & 63;
        int inc = h;
#pragma unroll
        for (int d = 1; d < 64; d <<= 1) {
            const int u = __shfl_up(inc, d);
            if (lane >= d) inc += u;
        }
        if (lane == 63) wse[tid >> 6] = inc;
        __syncthreads();
        int addp = 0;
        const int wv = tid >> 6;
#pragma unroll
        for (int w = 0; w < 4; ++w)
            if (w < wv) addp += wse[w];
        const int exc = inc - h + addp;
        off[tid] = exc;
        lcur[tid] = exc;
        if (tid == 255) off[NB] = inc + addp;
    }
    __syncthreads();
    // counting-sort scatter into LDS staging (bucket-contiguous)
    for (int j = 0; j < cnt; ++j) {
        const unsigned b = px[j] >> 24;
        const int p = atomicAdd(&lcur[b], 1);
        rec[p] = make_uint2(px[j], (unsigned)__float_as_int(fa[j]));
    }
    __syncthreads();
    // coalesced copy-out: consecutive i -> same-bucket run -> burst stores
    const int total = off[NB];
    for (int i = tid; i < total; i += PBK) {
        const uint2 e = rec[i];
        const unsigned b = e.x >> 24;
        const int pos = gbase[b] + (i - off[b]);
        if (pos < CAP) gEdges[(size_t)b * CAP + pos] = e;
    }
    // epilogue: block min/max -> private slot (no contended atomics)
#pragma unroll
    for (int m = 32; m >= 1; m >>= 1) {
        kmin = min(kmin, __shfl_xor(kmin, m));
        kmax = max(kmax, __shfl_xor(kmax, m));
    }
    const int wave = tid >> 6;
    if ((tid & 63) == 0) { smn[wave] = kmin; smx[wave] = kmax; }
    __syncthreads();
    if (tid == 0) {
#pragma unroll
        for (int w = 1; w < 4; ++w) {
            kmin = min(kmin, smn[w]);
            kmax = max(kmax, smx[w]);
        }
        mm[blockIdx.x] = make_int2(kmin, kmax);
    }
}

// K3: one 1024-thread block per FULL coarse bucket (256 blocks, ~51 KB LDS,
// single scan — R7, validated). Serial thread-0 prefix over 196 bins
// replaced by a 4-wave shfl scan: at 1 block/CU that loop was fully
// exposed (~1us/block).
// prologue: reduce the 391-entry per-edge-block minmax table;
// pass 1:   LDS histogram of the bucket's 196 rows;
// pass 2:   counting-sort scatter {col:u16, exp(minmaxnorm(score))};
// rows:     64 row-processors x 16 lanes (2 bf16 dims per lane via one u32
//           load), 4-way unrolled register accumulators, float2 out.
__global__ __launch_bounds__(1024, 1) void k_bucket(const int* __restrict__ gcount,
                                                    const uint2* __restrict__ gEdges,
                                                    const unsigned short* __restrict__ Xpb,
                                                    const int2* __restrict__ mm,
                                                    float* __restrict__ out) {
    __shared__ unsigned short scol[CAP]; // 16 KB
    __shared__ float swt[CAP];           // 32 KB
    __shared__ int off[RPB + 1];
    __shared__ int cur[RPB];
    __shared__ int wsc[4];
    __shared__ int rmn[16], rmx[16];
    __shared__ float s_mn, s_inv;
    const int b = blockIdx.x;
    const int t = threadIdx.x;
    const int cnt = min(gcount[b << 4], CAP);   // padded gcount
    const uint2* eb = gEdges + (size_t)b * CAP;

    // prologue: global min/max from the per-edge-block table
    int kmn = 0x7fffffff, kmx = 0x80000000;
    for (int i = t; i < NEB; i += 1024) {
        const int2 v = mm[i];
        kmn = min(kmn, v.x);
        kmx = max(kmx, v.y);
    }
#pragma unroll
    for (int m = 32; m >= 1; m >>= 1) {
        kmn = min(kmn, __shfl_xor(kmn, m));
        kmx = max(kmx, __shfl_xor(kmx, m));
    }
    if ((t & 63) == 0) { rmn[t >> 6] = kmn; rmx[t >> 6] = kmx; }
    if (t < RPB) cur[t] = 0;  // temp hist (same barrier covers this)
    __syncthreads();
    if (t == 0) {
#pragma unroll
        for (int w = 1; w < 16; ++w) {
            kmn = min(kmn, rmn[w]);
            kmx = max(kmx, rmx[w]);
        }
        const float mn = dec_f(kmn);
        const float mx = dec_f(kmx);
        s_mn = mn;
        s_inv = 1.0f / (mx - mn);
    }
    // pass 1: histogram of the bucket's rows
    for (int i = t; i < cnt; i += 1024)
        atomicAdd(&cur[(eb[i].x >> 16) & 0xFFu], 1);
    __syncthreads();
    // parallel exclusive scan of cur[0..195] -> off (first 4 waves)
    int inc_s = 0, v_s = 0;
    if (t < 256) {
        v_s = (t < RPB) ? cur[t] : 0;
        inc_s = v_s;
        const int lane = t & 63;
#pragma unroll
        for (int d = 1; d < 64; d <<= 1) {
            const int u = __shfl_up(inc_s, d);
            if (lane >= d) inc_s += u;
        }
        if (lane == 63) wsc[t >> 6] = inc_s;
    }
    __syncthreads();
    if (t < 256) {
        int addp = 0;
        const int wv = t >> 6;
#pragma unroll
        for (int w = 0; w < 4; ++w)
            if (w < wv) addp += wsc[w];
        if (t < RPB) off[t] = inc_s - v_s + addp;
        if (t == 255) off[RPB] = inc_s + addp;
    }
    __syncthreads();
    if (t < RPB) cur[t] = off[t];
    __syncthreads();
    const float mn = s_mn;
    const float inv = s_inv;
    // pass 2: counting-sort scatter (exp computed once per edge)
    for (int i = t; i < cnt; i += 1024) {
        const uint2 e = eb[i];
        const int lr = (int)((e.x >> 16) & 0xFFu);
        const int p = atomicAdd(&cur[lr], 1);
        if (p < CAP) {
            scol[p] = (unsigned short)(e.x & 0xFFFFu);
            swt[p] = __expf((__int_as_float(e.y) - mn) * inv);
        }
    }
    __syncthreads();

    // row processing: 64 processors x 16 lanes, 2 dims/lane, 4-way unroll
    const int proc = t >> 4;  // 0..63
    const int d2 = t & 15;    // dims [2*d2, 2*d2+1]
    const unsigned* Xp32 = (const unsigned*)Xpb;
    for (int lr = proc; lr < RPB; lr += 64) {
        const int s = off[lr];
        const int e2 = off[lr + 1];
        float pa0 = 0.f, pa1 = 0.f, pa2 = 0.f, pa3 = 0.f;
        float pb0 = 0.f, pb1 = 0.f, pb2 = 0.f, pb3 = 0.f;
        float w0s = 0.f, w1s = 0.f, w2s = 0.f, w3s = 0.f;
        int i = s;
        for (; i + 3 < e2; i += 4) {
            const int c0 = scol[i];
            const int c1 = scol[i + 1];
            const int c2 = scol[i + 2];
            const int c3 = scol[i + 3];
            const float w0 = swt[i];
            const float w1 = swt[i + 1];
            const float w2 = swt[i + 2];
            const float w3 = swt[i + 3];
            const unsigned u0 = Xp32[(size_t)c0 * 16 + d2];
            const unsigned u1 = Xp32[(size_t)c1 * 16 + d2];
            const unsigned u2 = Xp32[(size_t)c2 * 16 + d2];
            const unsigned u3 = Xp32[(size_t)c3 * 16 + d2];
            pa0 += w0 * bf2f((unsigned short)(u0 & 0xFFFFu));
            pb0 += w0 * bf2f((unsigned short)(u0 >> 16));
            pa1 += w1 * bf2f((unsigned short)(u1 & 0xFFFFu));
            pb1 += w1 * bf2f((unsigned short)(u1 >> 16));
            pa2 += w2 * bf2f((unsigned short)(u2 & 0xFFFFu));
            pb2 += w2 * bf2f((unsigned short)(u2 >> 16));
            pa3 += w3 * bf2f((unsigned short)(u3 & 0xFFFFu));
            pb3 += w3 * bf2f((unsigned short)(u3 >> 16));
            w0s += w0; w1s += w1; w2s += w2; w3s += w3;
        }
        for (; i < e2; ++i) {
            const float w = swt[i];
            const unsigned u = Xp32[(size_t)scol[i] * 16 + d2];
            pa0 += w * bf2f((unsigned short)(u & 0xFFFFu));
            pb0 += w * bf2f((unsigned short)(u >> 16));
            w0s += w;
        }
        const int r = b * RPB + lr;
        if (r < N_NODES) {
            const float ws = w0s + w1s + w2s + w3s;
            float2 o;
            o.x = (pa0 + pa1 + pa2 + pa3) / ws;
            o.y = (pb0 + pb1 + pb2 + pb3) / ws;
            ((float2*)out)[(size_t)r * 16 + d2] = o;
        }
    }
}

extern "C" void kernel_launch(void* const* d_in, const int* in_sizes, int n_in,
                              void* d_out, int out_size, void* d_ws, size_t ws_size,
                              hipStream_t stream) {
    const float* X  = (const float*)d_in[0];
    const float* W  = (const float*)d_in[1];
    const float* a0 = (const float*)d_in[2];
    const float* a1 = (const float*)d_in[3];
    const int* row  = (const int*)d_in[4];
    const int* col  = (const int*)d_in[5];
    float* out = (float*)d_out;

    // Workspace layout (4B units):
    // [pad: 64][gcount padded: NB*GST = 4096][mm: 1024]
    // [s0: 50048][s1: 50048][Xpb: 800000 u32][gEdges: NB*CAP uint2] ~20.4 MB
    float* ws = (float*)d_ws;
    int*   gcount = (int*)ws + 64;
    int2*  mm = (int2*)((int*)ws + 64 + NB * GST);
    float* s0 = ws + 64 + NB * GST + 1024;
    float* s1 = s0 + 50048;
    unsigned short* Xpb = (unsigned short*)(s1 + 50048);
    uint2* gEdges = (uint2*)(s1 + 50048 + 800000);

    k_gemm<<<NXB, 256, 0, stream>>>(X, W, a0, a1, Xpb, s0, s1, gcount);
    k_edge<<<NEB, 256, 0, stream>>>(row, col, s0, s1, gcount, mm, gEdges);
    k_bucket<<<NB, 1024, 0, stream>>>(gcount, gEdges, Xpb, mm, out);
}

// Round 10
// 140.317 us; speedup vs baseline: 1.3684x; 1.0156x over previous
//
#include <hip/hip_runtime.h>
#include <hip/hip_bf16.h>
#include <math.h>

#define N_NODES 50000
#define N_EDGES 1600000
#define D_IN 128
#define D_OUT 32
#define ALPHA 0.2f

#define NB   256     // coarse buckets (density: EB/NB = 16 rec/bkt/blk)
#define RPB  196     // rows per bucket (256*196 = 50176 >= 50000)
#define CAP  8192    // record slots per bucket (mean ~6250, +24 sigma)
#define GST  16      // gcount stride in ints: one counter per 64B line
#define PT   8       // edges per thread in edge kernel
#define EBK  512     // edge kernel block size (8 waves: latency hiding)
#define EB   (PT * EBK)                     // 4096 edges per edge-block
#define NEB  ((N_EDGES + EB - 1) / EB)      // 391 edge blocks
#define XNPB 64      // nodes per GEMM block (2 nodes/thread: W-reuse lever)
#define NXB  ((N_NODES + XNPB - 1) / XNPB)  // 782 GEMM blocks
#define XLS  33      // padded X-tile stride in float4 (bank-conflict fix)

// Monotone float<->int key (involution). Works with signed min/max.
__device__ __forceinline__ int enc_f(float x) {
    int i = __float_as_int(x);
    return i >= 0 ? i : (i ^ 0x7fffffff);
}
__device__ __forceinline__ float dec_f(int k) {
    return __int_as_float(k >= 0 ? k : (k ^ 0x7fffffff));
}
__device__ __forceinline__ unsigned short f2bf(float x) {
    __hip_bfloat16 h = __float2bfloat16(x);
    return *(unsigned short*)&h;
}
__device__ __forceinline__ float bf2f(unsigned short u) {
    return __uint_as_float((unsigned)u << 16);
}

// K1: GEMM X@W -> Xpb (bf16) with s0/s1 epilogue, 2 nodes per thread
// (W-reuse: per kk, 2 X + 4 W LDS reads feed 32 FMA4). Padded stride 33
// keeps both node rows conflict-free. Block 0 zeroes the padded gcount.
__global__ __launch_bounds__(256) void k_gemm(const float* __restrict__ X,
                                              const float* __restrict__ W,
                                              const float* __restrict__ a0,
                                              const float* __restrict__ a1,
                                              unsigned short* __restrict__ Xpb,
                                              float* __restrict__ s0,
                                              float* __restrict__ s1,
                                              int* __restrict__ gcount) {
    __shared__ float4 Wl4[1024];        // 16 KB
    __shared__ float4 Xl4[XNPB * XLS];  // 33.8 KB (padded)
    const int tid = threadIdx.x;
    if (blockIdx.x == 0) {
        int4* g4 = (int4*)gcount;
#pragma unroll
        for (int i = 0; i < NB * GST / 4 / 256; ++i)
            g4[tid + 256 * i] = make_int4(0, 0, 0, 0);
    }
    const int node0 = blockIdx.x * XNPB;
    {
        const float4* W4 = (const float4*)W;
#pragma unroll
        for (int i = 0; i < 4; ++i) Wl4[tid + 256 * i] = W4[tid + 256 * i];
        const float4* X4 = (const float4*)X + (size_t)node0 * (D_IN / 4);
        const int lim = (min(XNPB, N_NODES - node0)) * (D_IN / 4);
#pragma unroll
        for (int i = 0; i < 8; ++i) {
            const int idx = tid + 256 * i;
            const float4 v = (idx < lim) ? X4[idx]
                                         : make_float4(0.f, 0.f, 0.f, 0.f);
            Xl4[(idx >> 5) * XLS + (idx & 31)] = v;
        }
    }
    __syncthreads();
    const int g = tid >> 3;  // node pair (0..31): nodes g and g+32
    const int l = tid & 7;   // lane -> dims [4l, 4l+4)
    const float4* xr0 = &Xl4[g * XLS];
    const float4* xr1 = &Xl4[(g + 32) * XLS];
    float axA = 0.f, ayA = 0.f, azA = 0.f, awA = 0.f;
    float axB = 0.f, ayB = 0.f, azB = 0.f, awB = 0.f;
#pragma unroll 4
    for (int kk = 0; kk < D_IN / 4; ++kk) {
        const float4 xa = xr0[kk];
        const float4 xb = xr1[kk];
        const float4 w0 = Wl4[(4 * kk + 0) * 8 + l];
        const float4 w1 = Wl4[(4 * kk + 1) * 8 + l];
        const float4 w2 = Wl4[(4 * kk + 2) * 8 + l];
        const float4 w3 = Wl4[(4 * kk + 3) * 8 + l];
        axA += xa.x * w0.x + xa.y * w1.x + xa.z * w2.x + xa.w * w3.x;
        ayA += xa.x * w0.y + xa.y * w1.y + xa.z * w2.y + xa.w * w3.y;
        azA += xa.x * w0.z + xa.y * w1.z + xa.z * w2.z + xa.w * w3.z;
        awA += xa.x * w0.w + xa.y * w1.w + xa.z * w2.w + xa.w * w3.w;
        axB += xb.x * w0.x + xb.y * w1.x + xb.z * w2.x + xb.w * w3.x;
        ayB += xb.x * w0.y + xb.y * w1.y + xb.z * w2.y + xb.w * w3.y;
        azB += xb.x * w0.z + xb.y * w1.z + xb.z * w2.z + xb.w * w3.z;
        awB += xb.x * w0.w + xb.y * w1.w + xb.z * w2.w + xb.w * w3.w;
    }
    const float4 av0 = ((const float4*)a0)[l];
    const float4 av1 = ((const float4*)a1)[l];
    {   // node A = node0 + g
        const int node = node0 + g;
        if (node < N_NODES) {
            uint2 pk;
            pk.x = ((unsigned)f2bf(ayA) << 16) | f2bf(axA);
            pk.y = ((unsigned)f2bf(awA) << 16) | f2bf(azA);
            ((uint2*)Xpb)[(size_t)node * 8 + l] = pk;
            float v0 = axA * av0.x + ayA * av0.y + azA * av0.z + awA * av0.w;
            float v1 = axA * av1.x + ayA * av1.y + azA * av1.z + awA * av1.w;
#pragma unroll
            for (int m = 4; m >= 1; m >>= 1) {
                v0 += __shfl_xor(v0, m);
                v1 += __shfl_xor(v1, m);
            }
            if (l == 0) { s0[node] = v0; s1[node] = v1; }
        }
    }
    {   // node B = node0 + g + 32
        const int node = node0 + g + 32;
        if (node < N_NODES) {
            uint2 pk;
            pk.x = ((unsigned)f2bf(ayB) << 16) | f2bf(axB);
            pk.y = ((unsigned)f2bf(awB) << 16) | f2bf(azB);
            ((uint2*)Xpb)[(size_t)node * 8 + l] = pk;
            float v0 = axB * av0.x + ayB * av0.y + azB * av0.z + awB * av0.w;
            float v1 = axB * av1.x + ayB * av1.y + azB * av1.z + awB * av1.w;
#pragma unroll
            for (int m = 4; m >= 1; m >>= 1) {
                v0 += __shfl_xor(v0, m);
                v1 += __shfl_xor(v1, m);
            }
            if (l == 0) { s0[node] = v0; s1[node] = v1; }
        }
    }
}

// K2: edge pass v8 — R7's LDS-staged counting sort + coalesced write-out,
// now at 512 THREADS (8 waves/block). R8 analysis: 391 blocks x 4 waves
// was only ~6 waves/CU (grid-capped, LDS would allow 16) — every latency
// source (8K random s-gathers, 8/16-deep dependent LDS-atomic scatter
// chain, global claims) hidden only 6-deep. Same EB=4096 (density 16
// preserved), same staging; waves/CU ~12, per-thread chain halved (PT=8).
// hist/scan sections run on the first 4 waves (tid<256).
__global__ __launch_bounds__(512) void k_edge(const int* __restrict__ row,
                                              const int* __restrict__ col,
                                              const float* __restrict__ s0,
                                              const float* __restrict__ s1,
                                              int* __restrict__ gcount,
                                              int2* __restrict__ mm,
                                              uint2* __restrict__ gEdges) {
    __shared__ uint2 rec[EB];       // 32 KB staging
    __shared__ int hist[NB];        // 1 KB
    __shared__ int off[NB + 1];     // 1 KB: staging layout
    __shared__ int lcur[NB];        // 1 KB: staging cursors
    __shared__ int gbase[NB];       // 1 KB: claimed global bases
    __shared__ int wse[4];
    __shared__ int smn[8], smx[8];
    const int tid = threadIdx.x;
    if (tid < NB) hist[tid] = 0;
    __syncthreads();
    const int base = blockIdx.x * EB;
    unsigned px[PT];  // (b:8 | lr:8 | col:16)
    float    fa[PT];  // leaky-relu'd score
    int cnt = 0;
    int kmin = 0x7fffffff, kmax = 0x80000000;
    if (base + EB <= N_EDGES) {   // full block: int4 vector loads
#pragma unroll
        for (int i = 0; i < PT / 4; ++i) {
            const int4 r4 = ((const int4*)(row + base))[tid + i * EBK];
            const int4 c4 = ((const int4*)(col + base))[tid + i * EBK];
            const int rr[4] = {r4.x, r4.y, r4.z, r4.w};
            const int cc[4] = {c4.x, c4.y, c4.z, c4.w};
#pragma unroll
            for (int j = 0; j < 4; ++j) {
                const int r = rr[j];
                const int c = cc[j];
                float a = s0[r] + s1[c];
                a = a > 0.f ? a : ALPHA * a;
                const int k = enc_f(a);
                kmin = min(kmin, k);
                kmax = max(kmax, k);
                const unsigned b = (unsigned)r / RPB;
                const unsigned lr = (unsigned)r - b * RPB;
                px[cnt] = (b << 24) | (lr << 16) | (unsigned)c;
                fa[cnt] = a;
                ++cnt;
                atomicAdd(&hist[b], 1);
            }
        }
    } else {                      // tail block: scalar guarded
#pragma unroll
        for (int i = 0; i < PT; ++i) {
            const int e = base + i * EBK + tid;
            if (e >= N_EDGES) break;
            const int r = row[e];
            const int c = col[e];
            float a = s0[r] + s1[c];
            a = a > 0.f ? a : ALPHA * a;
            const int k = enc_f(a);
            kmin = min(kmin, k);
            kmax = max(kmax, k);
            const unsigned b = (unsigned)r / RPB;
            const unsigned lr = (unsigned)r - b * RPB;
            px[cnt] = (b << 24) | (lr << 16) | (unsigned)c;
            fa[cnt] = a;
            ++cnt;
            atomicAdd(&hist[b], 1);
        }
    }
    __syncthreads();
    // claim one contiguous global range per touched bucket (overlaps scan);
    // parallel exclusive scan of hist on the first 4 waves
    int h = 0, inc = 0;
    if (tid < NB) {
        h = hist[tid];
        gbase[tid] = h > 0 ? atomicAdd(&gcount[tid << 4], h) : 0;
        inc = h;
        const int lane = tid & 63;
#pragma unroll
        for (int d = 1; d < 64; d <<= 1) {
            const int u = __shfl_up(inc, d);
            if (lane >= d) inc += u;
        }
        if (lane == 63) wse[tid >> 6] = inc;
    }
    __syncthreads();
    if (tid < NB) {
        int addp = 0;
        const int wv = tid >> 6;
#pragma unroll
        for (int w = 0; w < 4; ++w)
            if (w < wv) addp += wse[w];
        const int exc = inc - h + addp;
        off[tid] = exc;
        lcur[tid] = exc;
        if (tid == NB - 1) off[NB] = inc + addp;
    }
    __syncthreads();
    // counting-sort scatter into LDS staging (bucket-contiguous)
    for (int j = 0; j < cnt; ++j) {
        const unsigned b = px[j] >> 24;
        const int p = atomicAdd(&lcur[b], 1);
        rec[p] = make_uint2(px[j], (unsigned)__float_as_int(fa[j]));
    }
    __syncthreads();
    // coalesced copy-out: consecutive i -> same-bucket run -> burst stores
    const int total = off[NB];
    for (int i = tid; i < total; i += EBK) {
        const uint2 e = rec[i];
        const unsigned b = e.x >> 24;
        const int pos = gbase[b] + (i - off[b]);
        if (pos < CAP) gEdges[(size_t)b * CAP + pos] = e;
    }
    // epilogue: block min/max -> private slot (no contended atomics)
#pragma unroll
    for (int m = 32; m >= 1; m >>= 1) {
        kmin = min(kmin, __shfl_xor(kmin, m));
        kmax = max(kmax, __shfl_xor(kmax, m));
    }
    const int wave = tid >> 6;
    if ((tid & 63) == 0) { smn[wave] = kmin; smx[wave] = kmax; }
    __syncthreads();
    if (tid == 0) {
#pragma unroll
        for (int w = 1; w < 8; ++w) {
            kmin = min(kmin, smn[w]);
            kmax = max(kmax, smx[w]);
        }
        mm[blockIdx.x] = make_int2(kmin, kmax);
    }
}

// K3: one 1024-thread block per FULL coarse bucket (256 blocks, ~51 KB LDS,
// single scan). Parallel 4-wave shfl scan for the 196-bin prefix.
// prologue: reduce the 391-entry per-edge-block minmax table;
// pass 1:   LDS histogram of the bucket's 196 rows;
// pass 2:   counting-sort scatter {col:u16, exp(minmaxnorm(score))};
// rows:     64 row-processors x 16 lanes (2 bf16 dims per lane via one u32
//           load), 4-way unrolled register accumulators, float2 out.
__global__ __launch_bounds__(1024, 1) void k_bucket(const int* __restrict__ gcount,
                                                    const uint2* __restrict__ gEdges,
                                                    const unsigned short* __restrict__ Xpb,
                                                    const int2* __restrict__ mm,
                                                    float* __restrict__ out) {
    __shared__ unsigned short scol[CAP]; // 16 KB
    __shared__ float swt[CAP];           // 32 KB
    __shared__ int off[RPB + 1];
    __shared__ int cur[RPB];
    __shared__ int wsc[4];
    __shared__ int rmn[16], rmx[16];
    __shared__ float s_mn, s_inv;
    const int b = blockIdx.x;
    const int t = threadIdx.x;
    const int cnt = min(gcount[b << 4], CAP);   // padded gcount
    const uint2* eb = gEdges + (size_t)b * CAP;

    // prologue: global min/max from the per-edge-block table
    int kmn = 0x7fffffff, kmx = 0x80000000;
    for (int i = t; i < NEB; i += 1024) {
        const int2 v = mm[i];
        kmn = min(kmn, v.x);
        kmx = max(kmx, v.y);
    }
#pragma unroll
    for (int m = 32; m >= 1; m >>= 1) {
        kmn = min(kmn, __shfl_xor(kmn, m));
        kmx = max(kmx, __shfl_xor(kmx, m));
    }
    if ((t & 63) == 0) { rmn[t >> 6] = kmn; rmx[t >> 6] = kmx; }
    if (t < RPB) cur[t] = 0;  // temp hist (same barrier covers this)
    __syncthreads();
    if (t == 0) {
#pragma unroll
        for (int w = 1; w < 16; ++w) {
            kmn = min(kmn, rmn[w]);
            kmx = max(kmx, rmx[w]);
        }
        const float mn = dec_f(kmn);
        const float mx = dec_f(kmx);
        s_mn = mn;
        s_inv = 1.0f / (mx - mn);
    }
    // pass 1: histogram of the bucket's rows
    for (int i = t; i < cnt; i += 1024)
        atomicAdd(&cur[(eb[i].x >> 16) & 0xFFu], 1);
    __syncthreads();
    // parallel exclusive scan of cur[0..195] -> off (first 4 waves)
    int inc_s = 0, v_s = 0;
    if (t < 256) {
        v_s = (t < RPB) ? cur[t] : 0;
        inc_s = v_s;
        const int lane = t & 63;
#pragma unroll
        for (int d = 1; d < 64; d <<= 1) {
            const int u = __shfl_up(inc_s, d);
            if (lane >= d) inc_s += u;
        }
        if (lane == 63) wsc[t >> 6] = inc_s;
    }
    __syncthreads();
    if (t < 256) {
        int addp = 0;
        const int wv = t >> 6;
#pragma unroll
        for (int w = 0; w < 4; ++w)
            if (w < wv) addp += wsc[w];
        if (t < RPB) off[t] = inc_s - v_s + addp;
        if (t == 255) off[RPB] = inc_s + addp;
    }
    __syncthreads();
    if (t < RPB) cur[t] = off[t];
    __syncthreads();
    const float mn = s_mn;
    const float inv = s_inv;
    // pass 2: counting-sort scatter (exp computed once per edge)
    for (int i = t; i < cnt; i += 1024) {
        const uint2 e = eb[i];
        const int lr = (int)((e.x >> 16) & 0xFFu);
        const int p = atomicAdd(&cur[lr], 1);
        if (p < CAP) {
            scol[p] = (unsigned short)(e.x & 0xFFFFu);
            swt[p] = __expf((__int_as_float(e.y) - mn) * inv);
        }
    }
    __syncthreads();

    // row processing: 64 processors x 16 lanes, 2 dims/lane, 4-way unroll
    const int proc = t >> 4;  // 0..63
    const int d2 = t & 15;    // dims [2*d2, 2*d2+1]
    const unsigned* Xp32 = (const unsigned*)Xpb;
    for (int lr = proc; lr < RPB; lr += 64) {
        const int s = off[lr];
        const int e2 = off[lr + 1];
        float pa0 = 0.f, pa1 = 0.f, pa2 = 0.f, pa3 = 0.f;
        float pb0 = 0.f, pb1 = 0.f, pb2 = 0.f, pb3 = 0.f;
        float w0s = 0.f, w1s = 0.f, w2s = 0.f, w3s = 0.f;
        int i = s;
        for (; i + 3 < e2; i += 4) {
            const int c0 = scol[i];
            const int c1 = scol[i + 1];
            const int c2 = scol[i + 2];
            const int c3 = scol[i + 3];
            const float w0 = swt[i];
            const float w1 = swt[i + 1];
            const float w2 = swt[i + 2];
            const float w3 = swt[i + 3];
            const unsigned u0 = Xp32[(size_t)c0 * 16 + d2];
            const unsigned u1 = Xp32[(size_t)c1 * 16 + d2];
            const unsigned u2 = Xp32[(size_t)c2 * 16 + d2];
            const unsigned u3 = Xp32[(size_t)c3 * 16 + d2];
            pa0 += w0 * bf2f((unsigned short)(u0 & 0xFFFFu));
            pb0 += w0 * bf2f((unsigned short)(u0 >> 16));
            pa1 += w1 * bf2f((unsigned short)(u1 & 0xFFFFu));
            pb1 += w1 * bf2f((unsigned short)(u1 >> 16));
            pa2 += w2 * bf2f((unsigned short)(u2 & 0xFFFFu));
            pb2 += w2 * bf2f((unsigned short)(u2 >> 16));
            pa3 += w3 * bf2f((unsigned short)(u3 & 0xFFFFu));
            pb3 += w3 * bf2f((unsigned short)(u3 >> 16));
            w0s += w0; w1s += w1; w2s += w2; w3s += w3;
        }
        for (; i < e2; ++i) {
            const float w = swt[i];
            const unsigned u = Xp32[(size_t)scol[i] * 16 + d2];
            pa0 += w * bf2f((unsigned short)(u & 0xFFFFu));
            pb0 += w * bf2f((unsigned short)(u >> 16));
            w0s += w;
        }
        const int r = b * RPB + lr;
        if (r < N_NODES) {
            const float ws = w0s + w1s + w2s + w3s;
            float2 o;
            o.x = (pa0 + pa1 + pa2 + pa3) / ws;
            o.y = (pb0 + pb1 + pb2 + pb3) / ws;
            ((float2*)out)[(size_t)r * 16 + d2] = o;
        }
    }
}

extern "C" void kernel_launch(void* const* d_in, const int* in_sizes, int n_in,
                              void* d_out, int out_size, void* d_ws, size_t ws_size,
                              hipStream_t stream) {
    const float* X  = (const float*)d_in[0];
    const float* W  = (const float*)d_in[1];
    const float* a0 = (const float*)d_in[2];
    const float* a1 = (const float*)d_in[3];
    const int* row  = (const int*)d_in[4];
    const int* col  = (const int*)d_in[5];
    float* out = (float*)d_out;

    // Workspace layout (4B units):
    // [pad: 64][gcount padded: NB*GST = 4096][mm: 1024]
    // [s0: 50048][s1: 50048][Xpb: 800000 u32][gEdges: NB*CAP uint2] ~20.4 MB
    float* ws = (float*)d_ws;
    int*   gcount = (int*)ws + 64;
    int2*  mm = (int2*)((int*)ws + 64 + NB * GST);
    float* s0 = ws + 64 + NB * GST + 1024;
    float* s1 = s0 + 50048;
    unsigned short* Xpb = (unsigned short*)(s1 + 50048);
    uint2* gEdges = (uint2*)(s1 + 50048 + 800000);

    k_gemm<<<NXB, 256, 0, stream>>>(X, W, a0, a1, Xpb, s0, s1, gcount);
    k_edge<<<NEB, 512, 0, stream>>>(row, col, s0, s1, gcount, mm, gEdges);
    k_bucket<<<NB, 1024, 0, stream>>>(gcount, gEdges, Xpb, mm, out);
}